// Round 8
// baseline (449.069 us; speedup 1.0000x reference)
//
#include <hip/hip_runtime.h>
#include <hip/hip_cooperative_groups.h>

typedef unsigned int u32;
typedef unsigned short u16;
typedef unsigned long long u64;

typedef short bf16x8 __attribute__((ext_vector_type(8)));
typedef float f32x4 __attribute__((ext_vector_type(4)));
typedef float f32x2 __attribute__((ext_vector_type(2)));

__device__ __forceinline__ float bl(u32 u){ return __uint_as_float(u << 16); }
__device__ __forceinline__ float bh(u32 u){ return __uint_as_float(u & 0xffff0000u); }
__device__ __forceinline__ float b16f(u16 r){ return __uint_as_float(((u32)r) << 16); }
__device__ __forceinline__ u16 f2b(float f){
  u32 u = __float_as_uint(f);
  u32 r = (u + 0x7fffu + ((u >> 16) & 1u)) >> 16;
  return (u16)r;
}
__device__ __forceinline__ u32 pk2(float a, float b){
  return (u32)f2b(a) | ((u32)f2b(b) << 16);
}
__device__ __forceinline__ void fma8(float* acc, float e2, uint2 h){
  f32x2 p0 = __builtin_amdgcn_cvt_pk_f32_fp8((int)h.x, 0);
  f32x2 p1 = __builtin_amdgcn_cvt_pk_f32_fp8((int)h.x, 1);
  f32x2 p2 = __builtin_amdgcn_cvt_pk_f32_fp8((int)h.y, 0);
  f32x2 p3 = __builtin_amdgcn_cvt_pk_f32_fp8((int)h.y, 1);
  acc[0]=fmaf(e2,p0.x,acc[0]); acc[1]=fmaf(e2,p0.y,acc[1]);
  acc[2]=fmaf(e2,p1.x,acc[2]); acc[3]=fmaf(e2,p1.y,acc[3]);
  acc[4]=fmaf(e2,p2.x,acc[4]); acc[5]=fmaf(e2,p2.y,acc[5]);
  acc[6]=fmaf(e2,p3.x,acc[6]); acc[7]=fmaf(e2,p3.y,acc[7]);
}

#define NEG_SLOPE 0.2f
#define BSTRIDE 4096   // slots per bucket region (max bucket ~3400 @ Poisson(3061))
#define SMBYTES 34816  // one shared buffer aliased by all phases (gemm Wt is largest)

// Stored-perm: pos p holds logical col c=(p&7)*16+(p>>3); fin unpermutes.

// ---------------- device bodies -----------

// Per-block dtype vote over x[0..255] (bf16: low-16 exponent in [110,135]).
__device__ __forceinline__ int detect_body(const u32* __restrict__ x, char* SM){
  int* cnt_ = (int*)SM;
  if (threadIdx.x == 0) *cnt_ = 0;
  __syncthreads();
  u32 w = x[threadIdx.x];
  int e = (int)((w >> 7) & 0xFFu);
  if (e >= 110 && e <= 135) atomicAdd(cnt_, 1);
  __syncthreads();
  return (*cnt_ >= 128) ? 1 : 0;
}

__device__ __forceinline__ void bnd_body(const int* __restrict__ batch,
    int* __restrict__ bnd, int N)
{
  int g = threadIdx.x;
  if (g <= 64){
    int lo = 0, hi = N;
    while (lo < hi){ int mid = (lo + hi) >> 1; if (batch[mid] < g) lo = mid + 1; else hi = mid; }
    bnd[g] = lo;
  }
}

// CSR pass A: bucket-partition edges by dst>>8 into breg.
__device__ __forceinline__ void part_body(const int* __restrict__ ei, int E, int nbuck,
    int* __restrict__ gcnt, u64* __restrict__ breg, int job, char* SM)
{
  u64* stage = (u64*)SM;                 // [2048] @0      (16384 B)
  u32* hist  = (u32*)(SM + 16384);       // [256]
  u32* lscan = (u32*)(SM + 17408);       // [257]
  u32* gbase = (u32*)(SM + 18436);       // [256]
  u32* cur   = (u32*)(SM + 19460);       // [256]  end 20484 < 34816
  const int tid = threadIdx.x;
  __syncthreads();                       // SM alias safety
  hist[tid] = 0; cur[tid] = 0;
  __syncthreads();
  const int e0 = job * 2048;
  int src[8], dst[8];
  #pragma unroll
  for (int j = 0; j < 8; j++){
    int t = e0 + tid + j*256;
    if (t < E){
      src[j] = ei[t]; dst[j] = ei[E + t];
      atomicAdd(&hist[dst[j] >> 8], 1u);
    } else dst[j] = -1;
  }
  __syncthreads();
  const u32 v = hist[tid];
  lscan[tid] = v;
  __syncthreads();
  for (int off = 1; off < 256; off <<= 1){
    u32 add = (tid >= off) ? lscan[tid - off] : 0;
    __syncthreads();
    lscan[tid] += add;
    __syncthreads();
  }
  if (tid == 255) lscan[256] = lscan[255];   // block total
  u32 excl = lscan[tid] - v;
  __syncthreads();
  const u32 total = lscan[256];
  lscan[tid] = excl;                          // exclusive scan in place
  if (tid < nbuck && v > 0) gbase[tid] = (u32)atomicAdd(&gcnt[tid], (int)v);
  __syncthreads();
  #pragma unroll
  for (int j = 0; j < 8; j++){
    if (dst[j] >= 0){
      int b = dst[j] >> 8;
      u32 p = lscan[b] + atomicAdd(&cur[b], 1u);
      stage[p] = ((u64)(u32)dst[j] << 32) | (u32)src[j];
    }
  }
  __syncthreads();
  for (u32 i = tid; i < total; i += 256){
    u64 e = stage[i];
    int b = (int)(e >> 40);                   // (dst>>8)
    u32 r = i - lscan[b];
    breg[(long)b * BSTRIDE + gbase[b] + r] = e;
  }
}

// CSR pass B: per-bucket compact CSR. rpd = (base+excl) | (deg<<20).
__device__ __forceinline__ void csr_body(const int* __restrict__ gcnt,
    const u64* __restrict__ breg,
    int* __restrict__ rpd, int* __restrict__ csrc, int N, int job, char* SM)
{
  u32* dl = (u32*)SM;
  u32* rp = dl + 256;
  u32* cu = rp + 256;
  const int b = job, tid = threadIdx.x;
  const int n0 = b << 8;
  __syncthreads();                       // SM alias safety
  const int cntb = gcnt[b];
  dl[tid] = 0; cu[tid] = 0;
  __syncthreads();
  const u64* reg = breg + (long)b * BSTRIDE;
  for (int i = tid; i < cntb; i += 256)
    atomicAdd(&dl[(int)(reg[i] >> 32) - n0], 1u);
  __syncthreads();
  const u32 v = dl[tid];
  rp[tid] = v;
  __syncthreads();
  for (int off = 1; off < 256; off <<= 1){
    u32 add = (tid >= off) ? rp[tid - off] : 0;
    __syncthreads();
    rp[tid] += add;
    __syncthreads();
  }
  u32 excl = rp[tid] - v;
  __syncthreads();
  rp[tid] = excl;
  __syncthreads();
  int node = n0 + tid;
  if (node < N) rpd[node] = (int)(((u32)(b*BSTRIDE) + excl) | (v << 20));
  for (int i = tid; i < cntb; i += 256){
    u64 e = reg[i];
    int d = (int)(e >> 32) - n0;
    u32 pos = rp[d] + atomicAdd(&cu[d], 1u);
    csrc[(long)b*BSTRIDE + pos] = (int)(e & 0xffffffffULL);
  }
}

// MFMA GEMM body: Hb[N,128] (fp8 e4m3, stored-perm cols) = X @ W.
// R8: fp32 W-staging unroll capped at 8 (unroll-64 held ~64 live VGPRs and
// set the whole megakernel's register budget -> occupancy cliff).
template<bool XEXT, bool KPERM>
__device__ __forceinline__ void gemm_body(int gb, int isbf,
    const void* __restrict__ Xv, const void* __restrict__ Wv,
    const void* __restrict__ av, const void* __restrict__ dv,
    u32* __restrict__ Hb, float* __restrict__ As, float* __restrict__ Ad, int N, char* SM)
{
  u16* Wt = (u16*)SM;              // [128*136] = 34816 B (pad 136: 2-way alias = free)
  const int tid = threadIdx.x;
  __syncthreads();                 // SM alias safety (prev job may still read)

  if (isbf){
    const u32* Wp = (const u32*)Wv;
    #pragma unroll
    for (int i = 0; i < 16; i++){
      int idx = tid + i*256;
      u32 p = Wp[idx];
      int k = idx >> 6, n2 = idx & 63;
      int pos = KPERM ? ((k & 15)*8 + (k >> 4)) : k;
      Wt[(2*n2)*136 + pos]   = (u16)(p & 0xffffu);
      Wt[(2*n2+1)*136 + pos] = (u16)(p >> 16);
    }
  } else {
    const float* Wf = (const float*)Wv;
    #pragma unroll 8
    for (int i = 0; i < 64; i++){
      int idx = tid + i*256;
      int k = idx >> 7, n = idx & 127;
      int pos = KPERM ? ((k & 15)*8 + (k >> 4)) : k;
      Wt[n*136 + pos] = f2b(Wf[idx]);
    }
  }
  __syncthreads();

  const int wv = tid >> 6, L = tid & 63;
  const int row0 = (gb*4 + wv) * 16;
  if (row0 >= N) return;
  const int nl = L & 15, quad = L >> 4;

  bf16x8 af[4];
  if (!XEXT || isbf){
    const uint4* Xr = (const uint4*)(((const u32*)Xv) + (long)row0*64);
    #pragma unroll
    for (int kb = 0; kb < 4; kb++)
      af[kb] = *(const bf16x8*)&Xr[nl*16 + kb*4 + quad];
  } else {
    const float* Xf = ((const float*)Xv) + (long)(row0 + nl)*128;
    #pragma unroll
    for (int kb = 0; kb < 4; kb++){
      const float4* p = (const float4*)(Xf + kb*32 + quad*8);
      float4 f0 = p[0], f1 = p[1];
      uint4 tmp = make_uint4(pk2(f0.x,f0.y), pk2(f0.z,f0.w), pk2(f1.x,f1.y), pk2(f1.z,f1.w));
      af[kb] = *(const bf16x8*)&tmp;
    }
  }

  f32x4 acc[8];
  #pragma unroll
  for (int nt = 0; nt < 8; nt++) acc[nt] = (f32x4){0.f,0.f,0.f,0.f};
  #pragma unroll
  for (int nt = 0; nt < 8; nt++){
    #pragma unroll
    for (int kb = 0; kb < 4; kb++){
      bf16x8 bf = *(const bf16x8*)&Wt[(nt*16 + nl)*136 + kb*32 + quad*8];
      acc[nt] = __builtin_amdgcn_mfma_f32_16x16x32_bf16(af[kb], bf, acc[nt], 0, 0, 0);
    }
  }

  float ps[4] = {0.f,0.f,0.f,0.f}, pd[4] = {0.f,0.f,0.f,0.f};
  #pragma unroll
  for (int nt = 0; nt < 8; nt++){
    int col = nt*16 + nl;
    float a_ = isbf ? b16f(((const u16*)av)[col]) : ((const float*)av)[col];
    float d_ = isbf ? b16f(((const u16*)dv)[col]) : ((const float*)dv)[col];
    #pragma unroll
    for (int r = 0; r < 4; r++){
      ps[r] = fmaf(acc[nt][r], a_, ps[r]);
      pd[r] = fmaf(acc[nt][r], d_, pd[r]);
    }
  }
  #pragma unroll
  for (int off = 1; off < 16; off <<= 1){
    #pragma unroll
    for (int r = 0; r < 4; r++){
      ps[r] += __shfl_xor(ps[r], off);
      pd[r] += __shfl_xor(pd[r], off);
    }
  }
  if (nl == 0){
    #pragma unroll
    for (int r = 0; r < 4; r++){
      As[row0 + quad*4 + r] = ps[r];
      Ad[row0 + quad*4 + r] = pd[r];
    }
  }

  #pragma unroll
  for (int r = 0; r < 4; r++){
    long row = row0 + quad*4 + r;
    int w0 = 0, w1 = 0;
    w0 = __builtin_amdgcn_cvt_pk_fp8_f32(acc[0][r], acc[1][r], w0, 0);
    w0 = __builtin_amdgcn_cvt_pk_fp8_f32(acc[2][r], acc[3][r], w0, 1);
    w1 = __builtin_amdgcn_cvt_pk_fp8_f32(acc[4][r], acc[5][r], w1, 0);
    w1 = __builtin_amdgcn_cvt_pk_fp8_f32(acc[6][r], acc[7][r], w1, 1);
    uint2 v = make_uint2((u32)w0, (u32)w1);
    *(uint2*)(Hb + row*32 + nl*2) = v;
  }
}

// Mean-pool partials. bnd[65] table in LDS -> no batch loads in hot loop.
__device__ __forceinline__ void pool_body(const u32* __restrict__ Ob,
    const int* __restrict__ bnd, float* __restrict__ psum, int N, int job, char* SM)
{
  int* bl_ = (int*)SM;                   // [65]
  const int tid = threadIdx.x;
  __syncthreads();                       // SM alias safety
  if (tid < 65) bl_[tid] = bnd[tid];
  __syncthreads();
  const int wv = tid >> 6, lane = tid & 63;
  const int start = job * 128;
  const int end = min(start + 128, N);
  int node = start + wv;
  if (node >= end) return;
  // largest g with bl_[g] <= node  (bl_[64]=N > node)
  int lo = 0, hi = 64;
  while (lo + 1 < hi){ int mid = (lo + hi) >> 1; if (bl_[mid] <= node) lo = mid; else hi = mid; }
  int cur = lo, nextb = bl_[cur + 1];
  float2 acc = make_float2(0.f, 0.f);
  const u32* __restrict__ ob = Ob + lane;
  for (int j = 0; j < 32; j += 4){
    int n0 = node + 4*j, n1 = n0 + 4, n2 = n0 + 8, n3 = n0 + 12;
    u32 p0 = 0, p1 = 0, p2 = 0, p3 = 0;
    if (n0 < end) p0 = ob[(long)n0*64];
    if (n1 < end) p1 = ob[(long)n1*64];
    if (n2 < end) p2 = ob[(long)n2*64];
    if (n3 < end) p3 = ob[(long)n3*64];
    #define PSTEP(nd, pv) \
      if (nd < end){ \
        while (nd >= nextb){ \
          atomicAdd(&psum[cur*128 + lane*2],     acc.x); \
          atomicAdd(&psum[cur*128 + lane*2 + 1], acc.y); \
          acc = make_float2(0.f, 0.f); \
          cur++; nextb = bl_[cur + 1]; \
        } \
        acc.x += bl(pv); acc.y += bh(pv); \
      }
    PSTEP(n0, p0) PSTEP(n1, p1) PSTEP(n2, p2) PSTEP(n3, p3)
    #undef PSTEP
  }
  atomicAdd(&psum[cur*128 + lane*2],     acc.x);
  atomicAdd(&psum[cur*128 + lane*2 + 1], acc.y);
}

// Fused per-node softmax-aggregate over fp8 Hb, 16 lanes/node, full-16 MLP.
// R8: s[]/ev[] arrays folded into consuming loops (shfl feeds address / fma
// directly) -> only h[16] stays live. Peak VGPR ~halved, MLP preserved.
template<bool RELU>
__device__ __forceinline__ void gath_body(const int* __restrict__ rpd,
    const int* __restrict__ csrc,
    const float* __restrict__ As, const float* __restrict__ Ad,
    const u32* __restrict__ Hb, const void* __restrict__ bv, int isbf,
    u32* __restrict__ Ob, int N, int job)
{
  long t = (long)job*256 + threadIdx.x;
  int node = (int)(t >> 4), q = (int)(t & 15);
  if (node >= N) return;
  const int base = threadIdx.x & 48;
  const float ad = Ad[node];
  const u32 pk = (u32)rpd[node];
  const int dg = (int)(pk >> 20);
  const int* row = csrc + (pk & 0xFFFFFu);
  float l = As[node] + ad;
  l = l > 0.f ? l : NEG_SLOPE * l;
  float e = __expf(l);
  float acc[8];
  {
    uint2 hv = ((const uint2*)(Hb + (long)node*32))[q];
    f32x2 p0 = __builtin_amdgcn_cvt_pk_f32_fp8((int)hv.x, 0);
    f32x2 p1 = __builtin_amdgcn_cvt_pk_f32_fp8((int)hv.x, 1);
    f32x2 p2 = __builtin_amdgcn_cvt_pk_f32_fp8((int)hv.y, 0);
    f32x2 p3 = __builtin_amdgcn_cvt_pk_f32_fp8((int)hv.y, 1);
    acc[0]=e*p0.x; acc[1]=e*p0.y; acc[2]=e*p1.x; acc[3]=e*p1.y;
    acc[4]=e*p2.x; acc[5]=e*p2.y; acc[6]=e*p3.x; acc[7]=e*p3.y;
  }
  float den = e;
  for (int jb = 0; jb < dg; jb += 16){
    int m = dg - jb; if (m > 16) m = 16;
    int sj = node;                         // tail lanes: e=0 (no-op), s=node (safe addr)
    if (q < m) sj = row[jb + q];
    float asv = As[sj];                    // gather issued early, overlaps below
    uint2 h[16];
    #pragma unroll
    for (int i = 0; i < 16; i++){
      int si = __shfl(sj, base + i);       // address dies at load issue
      h[i] = ((const uint2*)(Hb + (long)si*32))[q];
    }
    float evq = 0.f;
    if (q < m){
      float l2 = asv + ad;
      l2 = l2 > 0.f ? l2 : NEG_SLOPE * l2;
      evq = __expf(l2);
    }
    #pragma unroll
    for (int i = 0; i < 16; i++){
      float ei = __shfl(evq, base + i);
      den += ei;
      fma8(acc, ei, h[i]);
    }
  }
  float inv = 1.f / den;
  float b[8];
  if (isbf){
    const u16* bp = (const u16*)bv;
    #pragma unroll
    for (int i = 0; i < 8; i++) b[i] = b16f(bp[i*16 + q]);
  } else {
    const float* bp = (const float*)bv;
    #pragma unroll
    for (int i = 0; i < 8; i++) b[i] = bp[i*16 + q];
  }
  float o[8];
  #pragma unroll
  for (int i = 0; i < 8; i++){
    o[i] = fmaf(acc[i], inv, b[i]);
    if (RELU) o[i] = fmaxf(o[i], 0.f);
  }
  uint4 w = make_uint4(pk2(o[0],o[1]), pk2(o[2],o[3]), pk2(o[4],o[5]), pk2(o[6],o[7]));
  *(uint4*)&Ob[(long)node*64 + q*4] = w;
}

// Per-graph mean (counts from bnd), unpermute stored cols, store.
__device__ __forceinline__ void fin_body(const float* __restrict__ ps0,
    const float* __restrict__ ps1, const int* __restrict__ bnd,
    int isbf, void* __restrict__ out, int job)
{
  int t = job*256 + threadIdx.x;
  if (t >= 8192) return;
  int g = t >> 7, pos = t & 127;
  int c = ((pos & 7) << 4) + (pos >> 3);
  int cc = bnd[g+1] - bnd[g];
  float cf = (float)(cc < 1 ? 1 : cc);
  float v0 = ps0[t] / cf, v1 = ps1[t] / cf;
  if (isbf){
    u16* o = (u16*)out;
    o[g*128 + c] = f2b(v0); o[8192 + g*128 + c] = f2b(v1);
  } else {
    float* o = (float*)out;
    o[g*128 + c] = v0; o[8192 + g*128 + c] = v1;
  }
}

// ---------------- cooperative megakernel: whole pipeline, 1 dispatch ----------

struct MegaArgs {
  const u32* x; const int* ei; const int* batch;
  const void *W0, *as0, *ad0, *b0, *W1, *as1, *ad1, *b1;
  u32 *Hb, *Ob; float *As, *Ad;
  u64* breg; int *csrc, *rpd, *bnd, *gcnt;
  float *ps0, *ps1; void* out;
  int N, E, nbuck, gB, aB, nvB, pB;
};

__device__ __forceinline__ void mega_impl(MegaArgs& a)
{
  __shared__ __align__(16) char SM[SMBYTES];
  cooperative_groups::grid_group grid = cooperative_groups::this_grid();
  const int nb = (int)gridDim.x;
  const int isbf = detect_body(a.x, SM);

  // P0: gemm0 tiles [0,gB), bnd job gB, part tiles (gB, gB+aB]
  for (int j = blockIdx.x; j < a.gB + 1 + a.aB; j += nb){
    if (j < a.gB)       gemm_body<true,false>(j, isbf, a.x, a.W0, a.as0, a.ad0, a.Hb, a.As, a.Ad, a.N, SM);
    else if (j == a.gB) bnd_body(a.batch, a.bnd, a.N);
    else                part_body(a.ei, a.E, a.nbuck, a.gcnt, a.breg, j - a.gB - 1, SM);
  }
  grid.sync();
  // P1: csr (needs all part buckets)
  for (int j = blockIdx.x; j < a.nbuck; j += nb)
    csr_body(a.gcnt, a.breg, a.rpd, a.csrc, a.N, j, SM);
  grid.sync();
  // P2: layer-0 gather (+relu)
  for (int j = blockIdx.x; j < a.nvB; j += nb)
    gath_body<true>(a.rpd, a.csrc, a.As, a.Ad, a.Hb, a.b0, isbf, a.Ob, a.N, j);
  grid.sync();
  // P3: pool0 + gemm1 (independent jobs)
  for (int j = blockIdx.x; j < a.pB + a.gB; j += nb){
    if (j < a.pB) pool_body(a.Ob, a.bnd, a.ps0, a.N, j, SM);
    else          gemm_body<false,true>(j - a.pB, isbf, a.Ob, a.W1, a.as1, a.ad1, a.Hb, a.As, a.Ad, a.N, SM);
  }
  grid.sync();
  // P4: layer-1 gather
  for (int j = blockIdx.x; j < a.nvB; j += nb)
    gath_body<false>(a.rpd, a.csrc, a.As, a.Ad, a.Hb, a.b1, isbf, a.Ob, a.N, j);
  grid.sync();
  // P5: pool1
  for (int j = blockIdx.x; j < a.pB; j += nb)
    pool_body(a.Ob, a.bnd, a.ps1, a.N, j, SM);
  grid.sync();
  // P6: fin
  for (int j = blockIdx.x; j < 32; j += nb)
    fin_body(a.ps0, a.ps1, a.bnd, isbf, a.out, j);
}

// R7-proven unconstrained variant (172 VGPR, 2 waves/SIMD).
__global__ __launch_bounds__(256) void mega_k(MegaArgs a){ mega_impl(a); }

// R8: occupancy-targeted variant. 4 waves/EU -> VGPR cap 128 -> 16 waves/CU
// (LDS 34.8KB allows 4 blocks/CU). Host checks localSizeBytes==0 (no spills)
// before choosing it — R6's lesson: a cap WITH spills is a 5x regression.
__global__ __launch_bounds__(256) __attribute__((amdgpu_waves_per_eu(4)))
void mega_k4(MegaArgs a){ mega_impl(a); }

// ---------------- fallback standalone kernels (round-5 proven sequence) ------

__global__ __launch_bounds__(256) void gemmdet0_k(
    const u32* __restrict__ x, const int* __restrict__ batch, int* __restrict__ bnd,
    int* __restrict__ flag,
    const void* __restrict__ W0, const void* __restrict__ as0, const void* __restrict__ ad0,
    u32* __restrict__ Hb, float* __restrict__ As, float* __restrict__ Ad, int N, int gB)
{
  __shared__ __align__(16) char SM[SMBYTES];
  if ((int)blockIdx.x == gB){ bnd_body(batch, bnd, N); return; }
  int isbf = detect_body(x, SM);
  if (blockIdx.x == 0 && threadIdx.x == 0) *flag = isbf;
  gemm_body<true, false>(blockIdx.x, isbf, x, W0, as0, ad0, Hb, As, Ad, N, SM);
}

__global__ __launch_bounds__(256) void part_k(const int* __restrict__ ei, int E, int nbuck,
    int* __restrict__ gcnt, u64* __restrict__ breg)
{
  __shared__ __align__(16) char SM[SMBYTES];
  part_body(ei, E, nbuck, gcnt, breg, blockIdx.x, SM);
}

__global__ __launch_bounds__(256) void csr_k(const int* __restrict__ gcnt,
    const u64* __restrict__ breg,
    int* __restrict__ rpd, int* __restrict__ csrc, int N)
{
  __shared__ __align__(16) char SM[SMBYTES];
  csr_body(gcnt, breg, rpd, csrc, N, blockIdx.x, SM);
}

template<bool RELU>
__global__ __launch_bounds__(256) void gath_k(const int* __restrict__ rpd,
    const int* __restrict__ csrc,
    const float* __restrict__ As, const float* __restrict__ Ad,
    const u32* __restrict__ Hb, const void* __restrict__ bv, const int* __restrict__ flag,
    u32* __restrict__ Ob, int N)
{
  gath_body<RELU>(rpd, csrc, As, Ad, Hb, bv, *flag, Ob, N, blockIdx.x);
}

__global__ __launch_bounds__(256) void poolgemm1_k(
    const u32* __restrict__ Ob, const int* __restrict__ bnd, float* __restrict__ ps0, int pB,
    const void* __restrict__ W1, const void* __restrict__ as1, const void* __restrict__ ad1,
    const int* __restrict__ flag,
    u32* __restrict__ Hb, float* __restrict__ As, float* __restrict__ Ad, int N)
{
  __shared__ __align__(16) char SM[SMBYTES];
  if ((int)blockIdx.x < pB){ pool_body(Ob, bnd, ps0, N, blockIdx.x, SM); return; }
  gemm_body<false, true>(blockIdx.x - pB, *flag, Ob, W1, as1, ad1, Hb, As, Ad, N, SM);
}

__global__ __launch_bounds__(256) void pool2_k(const u32* __restrict__ Ob,
    const int* __restrict__ bnd, float* __restrict__ psum, int N)
{
  __shared__ __align__(16) char SM[SMBYTES];
  pool_body(Ob, bnd, psum, N, blockIdx.x, SM);
}

__global__ __launch_bounds__(256) void fin_k(const float* __restrict__ ps0,
    const float* __restrict__ ps1, const int* __restrict__ bnd,
    const int* __restrict__ flag, void* __restrict__ out)
{
  fin_body(ps0, ps1, bnd, *flag, out, blockIdx.x);
}

extern "C" void kernel_launch(void* const* d_in, const int* in_sizes, int n_in,
                              void* d_out, int out_size, void* d_ws, size_t ws_size,
                              hipStream_t stream)
{
  const void* x    = d_in[0];
  const int* ei    = (const int*)d_in[1];
  const int* batch = (const int*)d_in[3];
  const void* W0  = d_in[4];
  const void* as0 = d_in[5];
  const void* ad0 = d_in[6];
  const void* b0  = d_in[7];
  const void* W1  = d_in[8];
  const void* as1 = d_in[9];
  const void* ad1 = d_in[10];
  const void* b1  = d_in[11];

  const int N  = in_sizes[0] / 128;   // 50000
  const int E  = in_sizes[1] / 2;     // 600000
  const int nbuck = (N + 255) >> 8;   // 196 (must be <= 256)

  char* ws = (char*)d_ws;
  size_t off = 0;
  auto al = [&](size_t bytes){ size_t o = off; off += (bytes + 255) & ~(size_t)255; return o; };
  u32*   Hb    = (u32*)(ws + al((size_t)N*32*4));          // 6.4 MB fp8 H (perm cols)
  u32*   Ob    = (u32*)(ws + al((size_t)N*64*4));          // 12.8 MB bf16 out (perm cols)
  float* As    = (float*)(ws + al((size_t)N*4));
  float* Ad    = (float*)(ws + al((size_t)N*4));
  u64*   breg  = (u64*)(ws + al((size_t)nbuck*BSTRIDE*8)); // 6.4 MB bucketed (dst,src)
  int*   csrc  = (int*)(ws + al((size_t)nbuck*BSTRIDE*4)); // 3.2 MB compact CSR srcs
  int*   rpd   = (int*)(ws + al((size_t)N*4));             // rowptr | deg<<20
  int*   bnd   = (int*)(ws + al(512));                     // graph starts [65] (full 512B!)
  // contiguous zero region: ps0 + ps1 + gcnt (one memset)
  const size_t zbytes = 2*64*128*4 + 256*4;
  char*  z0    = ws + al(zbytes);
  float* ps0   = (float*)z0;
  float* ps1   = ps0 + 8192;
  int*   gcnt  = (int*)(ps1 + 8192);
  int*   flag  = (int*)(ws + al(256));
  if (off > ws_size) return;

  hipMemsetAsync(z0, 0, zbytes, stream);

  const int gB   = (N/16 + 3) / 4;        // gemm tiles (782)
  const int aB   = (E + 2047) / 2048;     // part tiles (293)
  const int nvB16= (N*16 + 255) / 256;    // gath tiles (3125)
  const int pB   = (N + 127) / 128;       // pool tiles (391)

  MegaArgs A;
  A.x = (const u32*)x; A.ei = ei; A.batch = batch;
  A.W0 = W0; A.as0 = as0; A.ad0 = ad0; A.b0 = b0;
  A.W1 = W1; A.as1 = as1; A.ad1 = ad1; A.b1 = b1;
  A.Hb = Hb; A.Ob = Ob; A.As = As; A.Ad = Ad;
  A.breg = breg; A.csrc = csrc; A.rpd = rpd; A.bnd = bnd; A.gcnt = gcnt;
  A.ps0 = ps0; A.ps1 = ps1; A.out = d_out;
  A.N = N; A.E = E; A.nbuck = nbuck; A.gB = gB; A.aB = aB; A.nvB = nvB16; A.pB = pB;

  // Choose mega variant: occupancy-targeted mega_k4 only if it compiled
  // spill-free; otherwise the R7-proven unconstrained mega_k.
  const void* kfun = (const void*)mega_k;
  hipFuncAttributes fa{};
  if (hipFuncGetAttributes(&fa, (const void*)mega_k4) == hipSuccess &&
      fa.localSizeBytes == 0)
    kfun = (const void*)mega_k4;

  int occ = 0;
  hipError_t qerr = hipOccupancyMaxActiveBlocksPerMultiprocessor(&occ, kfun, 256, 0);
  if (qerr == hipSuccess && occ >= 1){
    int grid = occ * 256;              // co-resident capacity (256 CUs)
    if (grid > 2048) grid = 2048;
    void* kargs[] = { (void*)&A };
    hipError_t err = hipLaunchCooperativeKernel(kfun,
        dim3(grid), dim3(256), kargs, 0, stream);
    if (err == hipSuccess) return;
  }

  // ---- fallback: proven round-5 dispatch sequence (same bodies) ----
  gemmdet0_k<<<gB + 1, 256, 0, stream>>>((const u32*)x, batch, bnd, flag,
      W0, as0, ad0, Hb, As, Ad, N, gB);
  part_k<<<aB, 256, 0, stream>>>(ei, E, nbuck, gcnt, breg);
  csr_k<<<nbuck, 256, 0, stream>>>(gcnt, breg, rpd, csrc, N);
  gath_k<true><<<nvB16, 256, 0, stream>>>(rpd, csrc, As, Ad, Hb, b0, flag, Ob, N);
  poolgemm1_k<<<pB + gB, 256, 0, stream>>>(Ob, bnd, ps0, pB,
      W1, as1, ad1, flag, Hb, As, Ad, N);
  gath_k<false><<<nvB16, 256, 0, stream>>>(rpd, csrc, As, Ad, Hb, b1, flag, Ob, N);
  pool2_k<<<pB, 256, 0, stream>>>(Ob, bnd, ps1, N);
  fin_k<<<32, 256, 0, stream>>>(ps0, ps1, bnd, flag, d_out);
}

// Round 9
// 447.904 us; speedup vs baseline: 1.0026x; 1.0026x over previous
//
#include <hip/hip_runtime.h>
#include <hip/hip_cooperative_groups.h>

typedef unsigned int u32;
typedef unsigned short u16;
typedef unsigned long long u64;

typedef short bf16x8 __attribute__((ext_vector_type(8)));
typedef float f32x4 __attribute__((ext_vector_type(4)));
typedef float f32x2 __attribute__((ext_vector_type(2)));

__device__ __forceinline__ float bl(u32 u){ return __uint_as_float(u << 16); }
__device__ __forceinline__ float bh(u32 u){ return __uint_as_float(u & 0xffff0000u); }
__device__ __forceinline__ float b16f(u16 r){ return __uint_as_float(((u32)r) << 16); }
__device__ __forceinline__ u16 f2b(float f){
  u32 u = __float_as_uint(f);
  u32 r = (u + 0x7fffu + ((u >> 16) & 1u)) >> 16;
  return (u16)r;
}
__device__ __forceinline__ u32 pk2(float a, float b){
  return (u32)f2b(a) | ((u32)f2b(b) << 16);
}
__device__ __forceinline__ void fma8(float* acc, float e2, uint2 h){
  f32x2 p0 = __builtin_amdgcn_cvt_pk_f32_fp8((int)h.x, 0);
  f32x2 p1 = __builtin_amdgcn_cvt_pk_f32_fp8((int)h.x, 1);
  f32x2 p2 = __builtin_amdgcn_cvt_pk_f32_fp8((int)h.y, 0);
  f32x2 p3 = __builtin_amdgcn_cvt_pk_f32_fp8((int)h.y, 1);
  acc[0]=fmaf(e2,p0.x,acc[0]); acc[1]=fmaf(e2,p0.y,acc[1]);
  acc[2]=fmaf(e2,p1.x,acc[2]); acc[3]=fmaf(e2,p1.y,acc[3]);
  acc[4]=fmaf(e2,p2.x,acc[4]); acc[5]=fmaf(e2,p2.y,acc[5]);
  acc[6]=fmaf(e2,p3.x,acc[6]); acc[7]=fmaf(e2,p3.y,acc[7]);
}

#define NEG_SLOPE 0.2f
#define BSTRIDE 4096   // slots per bucket region (max bucket ~3400 @ Poisson(3061))
#define SMBYTES 34816  // one shared buffer aliased by all phases (gemm Wt is largest)

// Stored-perm: pos p holds logical col c=(p&7)*16+(p>>3); fin unpermutes.

// ---------------- device bodies -----------

// Per-block dtype vote over x[0..255] (bf16: low-16 exponent in [110,135]).
__device__ __forceinline__ int detect_body(const u32* __restrict__ x, char* SM){
  int* cnt_ = (int*)SM;
  if (threadIdx.x == 0) *cnt_ = 0;
  __syncthreads();
  u32 w = x[threadIdx.x];
  int e = (int)((w >> 7) & 0xFFu);
  if (e >= 110 && e <= 135) atomicAdd(cnt_, 1);
  __syncthreads();
  return (*cnt_ >= 128) ? 1 : 0;
}

__device__ __forceinline__ void bnd_body(const int* __restrict__ batch,
    int* __restrict__ bnd, int N)
{
  int g = threadIdx.x;
  if (g <= 64){
    int lo = 0, hi = N;
    while (lo < hi){ int mid = (lo + hi) >> 1; if (batch[mid] < g) lo = mid + 1; else hi = mid; }
    bnd[g] = lo;
  }
}

// CSR pass A: bucket-partition edges by dst>>8 into breg.
__device__ __forceinline__ void part_body(const int* __restrict__ ei, int E, int nbuck,
    int* __restrict__ gcnt, u64* __restrict__ breg, int job, char* SM)
{
  u64* stage = (u64*)SM;                 // [2048] @0      (16384 B)
  u32* hist  = (u32*)(SM + 16384);       // [256]
  u32* lscan = (u32*)(SM + 17408);       // [257]
  u32* gbase = (u32*)(SM + 18436);       // [256]
  u32* cur   = (u32*)(SM + 19460);       // [256]  end 20484 < 34816
  const int tid = threadIdx.x;
  __syncthreads();                       // SM alias safety
  hist[tid] = 0; cur[tid] = 0;
  __syncthreads();
  const int e0 = job * 2048;
  int src[8], dst[8];
  #pragma unroll
  for (int j = 0; j < 8; j++){
    int t = e0 + tid + j*256;
    if (t < E){
      src[j] = ei[t]; dst[j] = ei[E + t];
      atomicAdd(&hist[dst[j] >> 8], 1u);
    } else dst[j] = -1;
  }
  __syncthreads();
  const u32 v = hist[tid];
  lscan[tid] = v;
  __syncthreads();
  for (int off = 1; off < 256; off <<= 1){
    u32 add = (tid >= off) ? lscan[tid - off] : 0;
    __syncthreads();
    lscan[tid] += add;
    __syncthreads();
  }
  if (tid == 255) lscan[256] = lscan[255];   // block total
  u32 excl = lscan[tid] - v;
  __syncthreads();
  const u32 total = lscan[256];
  lscan[tid] = excl;                          // exclusive scan in place
  if (tid < nbuck && v > 0) gbase[tid] = (u32)atomicAdd(&gcnt[tid], (int)v);
  __syncthreads();
  #pragma unroll
  for (int j = 0; j < 8; j++){
    if (dst[j] >= 0){
      int b = dst[j] >> 8;
      u32 p = lscan[b] + atomicAdd(&cur[b], 1u);
      stage[p] = ((u64)(u32)dst[j] << 32) | (u32)src[j];
    }
  }
  __syncthreads();
  for (u32 i = tid; i < total; i += 256){
    u64 e = stage[i];
    int b = (int)(e >> 40);                   // (dst>>8)
    u32 r = i - lscan[b];
    breg[(long)b * BSTRIDE + gbase[b] + r] = e;
  }
}

// CSR pass B: per-bucket compact CSR. rpd = (base+excl) | (deg<<20).
__device__ __forceinline__ void csr_body(const int* __restrict__ gcnt,
    const u64* __restrict__ breg,
    int* __restrict__ rpd, int* __restrict__ csrc, int N, int job, char* SM)
{
  u32* dl = (u32*)SM;
  u32* rp = dl + 256;
  u32* cu = rp + 256;
  const int b = job, tid = threadIdx.x;
  const int n0 = b << 8;
  __syncthreads();                       // SM alias safety
  const int cntb = gcnt[b];
  dl[tid] = 0; cu[tid] = 0;
  __syncthreads();
  const u64* reg = breg + (long)b * BSTRIDE;
  for (int i = tid; i < cntb; i += 256)
    atomicAdd(&dl[(int)(reg[i] >> 32) - n0], 1u);
  __syncthreads();
  const u32 v = dl[tid];
  rp[tid] = v;
  __syncthreads();
  for (int off = 1; off < 256; off <<= 1){
    u32 add = (tid >= off) ? rp[tid - off] : 0;
    __syncthreads();
    rp[tid] += add;
    __syncthreads();
  }
  u32 excl = rp[tid] - v;
  __syncthreads();
  rp[tid] = excl;
  __syncthreads();
  int node = n0 + tid;
  if (node < N) rpd[node] = (int)(((u32)(b*BSTRIDE) + excl) | (v << 20));
  for (int i = tid; i < cntb; i += 256){
    u64 e = reg[i];
    int d = (int)(e >> 32) - n0;
    u32 pos = rp[d] + atomicAdd(&cu[d], 1u);
    csrc[(long)b*BSTRIDE + pos] = (int)(e & 0xffffffffULL);
  }
}

// MFMA GEMM body: Hb[N,128] (fp8 e4m3, stored-perm cols) = X @ W.
// R9: nt-loop split into two halves with acc[4] (was acc[8]) -> -16 VGPR;
// W-staging unrolls capped at 8 -> fewer live staging regs. Same MFMA count,
// identical numerics and Hb/As/Ad layout (half h writes u32[h] of the uint2).
template<bool XEXT, bool KPERM>
__device__ __forceinline__ void gemm_body(int gb, int isbf,
    const void* __restrict__ Xv, const void* __restrict__ Wv,
    const void* __restrict__ av, const void* __restrict__ dv,
    u32* __restrict__ Hb, float* __restrict__ As, float* __restrict__ Ad, int N, char* SM)
{
  u16* Wt = (u16*)SM;              // [128*136] = 34816 B (pad 136: 2-way alias = free)
  const int tid = threadIdx.x;
  __syncthreads();                 // SM alias safety (prev job may still read)

  if (isbf){
    const u32* Wp = (const u32*)Wv;
    #pragma unroll 8
    for (int i = 0; i < 16; i++){
      int idx = tid + i*256;
      u32 p = Wp[idx];
      int k = idx >> 6, n2 = idx & 63;
      int pos = KPERM ? ((k & 15)*8 + (k >> 4)) : k;
      Wt[(2*n2)*136 + pos]   = (u16)(p & 0xffffu);
      Wt[(2*n2+1)*136 + pos] = (u16)(p >> 16);
    }
  } else {
    const float* Wf = (const float*)Wv;
    #pragma unroll 8
    for (int i = 0; i < 64; i++){
      int idx = tid + i*256;
      int k = idx >> 7, n = idx & 127;
      int pos = KPERM ? ((k & 15)*8 + (k >> 4)) : k;
      Wt[n*136 + pos] = f2b(Wf[idx]);
    }
  }
  __syncthreads();

  const int wv = tid >> 6, L = tid & 63;
  const int row0 = (gb*4 + wv) * 16;
  if (row0 >= N) return;
  const int nl = L & 15, quad = L >> 4;

  bf16x8 af[4];
  if (!XEXT || isbf){
    const uint4* Xr = (const uint4*)(((const u32*)Xv) + (long)row0*64);
    #pragma unroll
    for (int kb = 0; kb < 4; kb++)
      af[kb] = *(const bf16x8*)&Xr[nl*16 + kb*4 + quad];
  } else {
    const float* Xf = ((const float*)Xv) + (long)(row0 + nl)*128;
    #pragma unroll
    for (int kb = 0; kb < 4; kb++){
      const float4* p = (const float4*)(Xf + kb*32 + quad*8);
      float4 f0 = p[0], f1 = p[1];
      uint4 tmp = make_uint4(pk2(f0.x,f0.y), pk2(f0.z,f0.w), pk2(f1.x,f1.y), pk2(f1.z,f1.w));
      af[kb] = *(const bf16x8*)&tmp;
    }
  }

  float ps[4] = {0.f,0.f,0.f,0.f}, pd[4] = {0.f,0.f,0.f,0.f};
  #pragma unroll
  for (int half = 0; half < 2; half++){
    f32x4 acc[4];
    #pragma unroll
    for (int nt = 0; nt < 4; nt++) acc[nt] = (f32x4){0.f,0.f,0.f,0.f};
    #pragma unroll
    for (int nt = 0; nt < 4; nt++){
      #pragma unroll
      for (int kb = 0; kb < 4; kb++){
        bf16x8 bf = *(const bf16x8*)&Wt[((half*4 + nt)*16 + nl)*136 + kb*32 + quad*8];
        acc[nt] = __builtin_amdgcn_mfma_f32_16x16x32_bf16(af[kb], bf, acc[nt], 0, 0, 0);
      }
    }
    #pragma unroll
    for (int nt = 0; nt < 4; nt++){
      int col = (half*4 + nt)*16 + nl;
      float a_ = isbf ? b16f(((const u16*)av)[col]) : ((const float*)av)[col];
      float d_ = isbf ? b16f(((const u16*)dv)[col]) : ((const float*)dv)[col];
      #pragma unroll
      for (int r = 0; r < 4; r++){
        ps[r] = fmaf(acc[nt][r], a_, ps[r]);
        pd[r] = fmaf(acc[nt][r], d_, pd[r]);
      }
    }
    #pragma unroll
    for (int r = 0; r < 4; r++){
      long row = row0 + quad*4 + r;
      int w = 0;
      w = __builtin_amdgcn_cvt_pk_fp8_f32(acc[0][r], acc[1][r], w, 0);
      w = __builtin_amdgcn_cvt_pk_fp8_f32(acc[2][r], acc[3][r], w, 1);
      (Hb + row*32 + nl*2)[half] = (u32)w;
    }
  }

  #pragma unroll
  for (int off = 1; off < 16; off <<= 1){
    #pragma unroll
    for (int r = 0; r < 4; r++){
      ps[r] += __shfl_xor(ps[r], off);
      pd[r] += __shfl_xor(pd[r], off);
    }
  }
  if (nl == 0){
    #pragma unroll
    for (int r = 0; r < 4; r++){
      As[row0 + quad*4 + r] = ps[r];
      Ad[row0 + quad*4 + r] = pd[r];
    }
  }
}

// Mean-pool partials. bnd[65] table in LDS -> no batch loads in hot loop.
__device__ __forceinline__ void pool_body(const u32* __restrict__ Ob,
    const int* __restrict__ bnd, float* __restrict__ psum, int N, int job, char* SM)
{
  int* bl_ = (int*)SM;                   // [65]
  const int tid = threadIdx.x;
  __syncthreads();                       // SM alias safety
  if (tid < 65) bl_[tid] = bnd[tid];
  __syncthreads();
  const int wv = tid >> 6, lane = tid & 63;
  const int start = job * 128;
  const int end = min(start + 128, N);
  int node = start + wv;
  if (node >= end) return;
  // largest g with bl_[g] <= node  (bl_[64]=N > node)
  int lo = 0, hi = 64;
  while (lo + 1 < hi){ int mid = (lo + hi) >> 1; if (bl_[mid] <= node) lo = mid; else hi = mid; }
  int cur = lo, nextb = bl_[cur + 1];
  float2 acc = make_float2(0.f, 0.f);
  const u32* __restrict__ ob = Ob + lane;
  for (int j = 0; j < 32; j += 4){
    int n0 = node + 4*j, n1 = n0 + 4, n2 = n0 + 8, n3 = n0 + 12;
    u32 p0 = 0, p1 = 0, p2 = 0, p3 = 0;
    if (n0 < end) p0 = ob[(long)n0*64];
    if (n1 < end) p1 = ob[(long)n1*64];
    if (n2 < end) p2 = ob[(long)n2*64];
    if (n3 < end) p3 = ob[(long)n3*64];
    #define PSTEP(nd, pv) \
      if (nd < end){ \
        while (nd >= nextb){ \
          atomicAdd(&psum[cur*128 + lane*2],     acc.x); \
          atomicAdd(&psum[cur*128 + lane*2 + 1], acc.y); \
          acc = make_float2(0.f, 0.f); \
          cur++; nextb = bl_[cur + 1]; \
        } \
        acc.x += bl(pv); acc.y += bh(pv); \
      }
    PSTEP(n0, p0) PSTEP(n1, p1) PSTEP(n2, p2) PSTEP(n3, p3)
    #undef PSTEP
  }
  atomicAdd(&psum[cur*128 + lane*2],     acc.x);
  atomicAdd(&psum[cur*128 + lane*2 + 1], acc.y);
}

// Fused per-node softmax-aggregate over fp8 Hb, 16 lanes/node, full-16 MLP.
// R9: REVERTED to the R7 batched form. R8's fold (shfl feeding each load)
// serialized 16 ds_bpermute+lgkmcnt round-trips into the tile critical path
// (bench 182.7 -> 449 us). Batched s[16] -> one lgkmcnt wait -> 16 loads in
// flight is the required MLP structure; do not fold.
template<bool RELU>
__device__ __forceinline__ void gath_body(const int* __restrict__ rpd,
    const int* __restrict__ csrc,
    const float* __restrict__ As, const float* __restrict__ Ad,
    const u32* __restrict__ Hb, const void* __restrict__ bv, int isbf,
    u32* __restrict__ Ob, int N, int job)
{
  long t = (long)job*256 + threadIdx.x;
  int node = (int)(t >> 4), q = (int)(t & 15);
  if (node >= N) return;
  const int base = threadIdx.x & 48;
  const float ad = Ad[node];
  const u32 pk = (u32)rpd[node];
  const int dg = (int)(pk >> 20);
  const int* row = csrc + (pk & 0xFFFFFu);
  float l = As[node] + ad;
  l = l > 0.f ? l : NEG_SLOPE * l;
  float e = __expf(l);
  float acc[8];
  {
    uint2 hv = ((const uint2*)(Hb + (long)node*32))[q];
    f32x2 p0 = __builtin_amdgcn_cvt_pk_f32_fp8((int)hv.x, 0);
    f32x2 p1 = __builtin_amdgcn_cvt_pk_f32_fp8((int)hv.x, 1);
    f32x2 p2 = __builtin_amdgcn_cvt_pk_f32_fp8((int)hv.y, 0);
    f32x2 p3 = __builtin_amdgcn_cvt_pk_f32_fp8((int)hv.y, 1);
    acc[0]=e*p0.x; acc[1]=e*p0.y; acc[2]=e*p1.x; acc[3]=e*p1.y;
    acc[4]=e*p2.x; acc[5]=e*p2.y; acc[6]=e*p3.x; acc[7]=e*p3.y;
  }
  float den = e;
  for (int jb = 0; jb < dg; jb += 16){
    int m = dg - jb; if (m > 16) m = 16;
    int sj = node;                         // tail lanes: e=0 (no-op), s=node (safe addr)
    if (q < m) sj = row[jb + q];
    float asv = As[sj];                    // gather issued early, overlaps below
    int s[16];
    #pragma unroll
    for (int i = 0; i < 16; i++) s[i] = __shfl(sj, base + i);
    uint2 h[16];
    #pragma unroll
    for (int i = 0; i < 16; i++) h[i] = ((const uint2*)(Hb + (long)s[i]*32))[q];
    float evq = 0.f;
    if (q < m){
      float l2 = asv + ad;
      l2 = l2 > 0.f ? l2 : NEG_SLOPE * l2;
      evq = __expf(l2);
    }
    float ev[16];
    #pragma unroll
    for (int i = 0; i < 16; i++) ev[i] = __shfl(evq, base + i);
    float dsum = 0.f;
    #pragma unroll
    for (int i = 0; i < 16; i++) dsum += ev[i];
    den += dsum;
    #pragma unroll
    for (int i = 0; i < 16; i++) fma8(acc, ev[i], h[i]);
  }
  float inv = 1.f / den;
  float b[8];
  if (isbf){
    const u16* bp = (const u16*)bv;
    #pragma unroll
    for (int i = 0; i < 8; i++) b[i] = b16f(bp[i*16 + q]);
  } else {
    const float* bp = (const float*)bv;
    #pragma unroll
    for (int i = 0; i < 8; i++) b[i] = bp[i*16 + q];
  }
  float o[8];
  #pragma unroll
  for (int i = 0; i < 8; i++){
    o[i] = fmaf(acc[i], inv, b[i]);
    if (RELU) o[i] = fmaxf(o[i], 0.f);
  }
  uint4 w = make_uint4(pk2(o[0],o[1]), pk2(o[2],o[3]), pk2(o[4],o[5]), pk2(o[6],o[7]));
  *(uint4*)&Ob[(long)node*64 + q*4] = w;
}

// Per-graph mean (counts from bnd), unpermute stored cols, store.
__device__ __forceinline__ void fin_body(const float* __restrict__ ps0,
    const float* __restrict__ ps1, const int* __restrict__ bnd,
    int isbf, void* __restrict__ out, int job)
{
  int t = job*256 + threadIdx.x;
  if (t >= 8192) return;
  int g = t >> 7, pos = t & 127;
  int c = ((pos & 7) << 4) + (pos >> 3);
  int cc = bnd[g+1] - bnd[g];
  float cf = (float)(cc < 1 ? 1 : cc);
  float v0 = ps0[t] / cf, v1 = ps1[t] / cf;
  if (isbf){
    u16* o = (u16*)out;
    o[g*128 + c] = f2b(v0); o[8192 + g*128 + c] = f2b(v1);
  } else {
    float* o = (float*)out;
    o[g*128 + c] = v0; o[8192 + g*128 + c] = v1;
  }
}

// ---------------- cooperative megakernel: whole pipeline, 1 dispatch ----------

struct MegaArgs {
  const u32* x; const int* ei; const int* batch;
  const void *W0, *as0, *ad0, *b0, *W1, *as1, *ad1, *b1;
  u32 *Hb, *Ob; float *As, *Ad;
  u64* breg; int *csrc, *rpd, *bnd, *gcnt;
  float *ps0, *ps1; void* out;
  int N, E, nbuck, gB, aB, nvB, pB;
};

__device__ __forceinline__ void mega_impl(MegaArgs& a)
{
  __shared__ __align__(16) char SM[SMBYTES];
  cooperative_groups::grid_group grid = cooperative_groups::this_grid();
  const int nb = (int)gridDim.x;
  const int isbf = detect_body(a.x, SM);

  // P0: gemm0 tiles [0,gB), bnd job gB, part tiles (gB, gB+aB]
  for (int j = blockIdx.x; j < a.gB + 1 + a.aB; j += nb){
    if (j < a.gB)       gemm_body<true,false>(j, isbf, a.x, a.W0, a.as0, a.ad0, a.Hb, a.As, a.Ad, a.N, SM);
    else if (j == a.gB) bnd_body(a.batch, a.bnd, a.N);
    else                part_body(a.ei, a.E, a.nbuck, a.gcnt, a.breg, j - a.gB - 1, SM);
  }
  grid.sync();
  // P1: csr (needs all part buckets)
  for (int j = blockIdx.x; j < a.nbuck; j += nb)
    csr_body(a.gcnt, a.breg, a.rpd, a.csrc, a.N, j, SM);
  grid.sync();
  // P2: layer-0 gather (+relu)
  for (int j = blockIdx.x; j < a.nvB; j += nb)
    gath_body<true>(a.rpd, a.csrc, a.As, a.Ad, a.Hb, a.b0, isbf, a.Ob, a.N, j);
  grid.sync();
  // P3: pool0 + gemm1 (independent jobs)
  for (int j = blockIdx.x; j < a.pB + a.gB; j += nb){
    if (j < a.pB) pool_body(a.Ob, a.bnd, a.ps0, a.N, j, SM);
    else          gemm_body<false,true>(j - a.pB, isbf, a.Ob, a.W1, a.as1, a.ad1, a.Hb, a.As, a.Ad, a.N, SM);
  }
  grid.sync();
  // P4: layer-1 gather
  for (int j = blockIdx.x; j < a.nvB; j += nb)
    gath_body<false>(a.rpd, a.csrc, a.As, a.Ad, a.Hb, a.b1, isbf, a.Ob, a.N, j);
  grid.sync();
  // P5: pool1
  for (int j = blockIdx.x; j < a.pB; j += nb)
    pool_body(a.Ob, a.bnd, a.ps1, a.N, j, SM);
  grid.sync();
  // P6: fin
  for (int j = blockIdx.x; j < 32; j += nb)
    fin_body(a.ps0, a.ps1, a.bnd, isbf, a.out, j);
}

// Unconstrained (R7-proven floor).
__global__ __launch_bounds__(256) void mega_k(MegaArgs a){ mega_impl(a); }
// 3 waves/EU: VGPR cap ~170 (R7 was 172 — just over this edge) -> 3 blocks/CU.
__global__ __launch_bounds__(256) __attribute__((amdgpu_waves_per_eu(3)))
void mega_k3(MegaArgs a){ mega_impl(a); }
// 4 waves/EU: VGPR cap 128 -> 4 blocks/CU (LDS limit). Only used if spill-free.
__global__ __launch_bounds__(256) __attribute__((amdgpu_waves_per_eu(4)))
void mega_k4(MegaArgs a){ mega_impl(a); }

// ---------------- fallback standalone kernels (round-5 proven sequence) ------

__global__ __launch_bounds__(256) void gemmdet0_k(
    const u32* __restrict__ x, const int* __restrict__ batch, int* __restrict__ bnd,
    int* __restrict__ flag,
    const void* __restrict__ W0, const void* __restrict__ as0, const void* __restrict__ ad0,
    u32* __restrict__ Hb, float* __restrict__ As, float* __restrict__ Ad, int N, int gB)
{
  __shared__ __align__(16) char SM[SMBYTES];
  if ((int)blockIdx.x == gB){ bnd_body(batch, bnd, N); return; }
  int isbf = detect_body(x, SM);
  if (blockIdx.x == 0 && threadIdx.x == 0) *flag = isbf;
  gemm_body<true, false>(blockIdx.x, isbf, x, W0, as0, ad0, Hb, As, Ad, N, SM);
}

__global__ __launch_bounds__(256) void part_k(const int* __restrict__ ei, int E, int nbuck,
    int* __restrict__ gcnt, u64* __restrict__ breg)
{
  __shared__ __align__(16) char SM[SMBYTES];
  part_body(ei, E, nbuck, gcnt, breg, blockIdx.x, SM);
}

__global__ __launch_bounds__(256) void csr_k(const int* __restrict__ gcnt,
    const u64* __restrict__ breg,
    int* __restrict__ rpd, int* __restrict__ csrc, int N)
{
  __shared__ __align__(16) char SM[SMBYTES];
  csr_body(gcnt, breg, rpd, csrc, N, blockIdx.x, SM);
}

template<bool RELU>
__global__ __launch_bounds__(256) void gath_k(const int* __restrict__ rpd,
    const int* __restrict__ csrc,
    const float* __restrict__ As, const float* __restrict__ Ad,
    const u32* __restrict__ Hb, const void* __restrict__ bv, const int* __restrict__ flag,
    u32* __restrict__ Ob, int N)
{
  gath_body<RELU>(rpd, csrc, As, Ad, Hb, bv, *flag, Ob, N, blockIdx.x);
}

__global__ __launch_bounds__(256) void poolgemm1_k(
    const u32* __restrict__ Ob, const int* __restrict__ bnd, float* __restrict__ ps0, int pB,
    const void* __restrict__ W1, const void* __restrict__ as1, const void* __restrict__ ad1,
    const int* __restrict__ flag,
    u32* __restrict__ Hb, float* __restrict__ As, float* __restrict__ Ad, int N)
{
  __shared__ __align__(16) char SM[SMBYTES];
  if ((int)blockIdx.x < pB){ pool_body(Ob, bnd, ps0, N, blockIdx.x, SM); return; }
  gemm_body<false, true>(blockIdx.x - pB, *flag, Ob, W1, as1, ad1, Hb, As, Ad, N, SM);
}

__global__ __launch_bounds__(256) void pool2_k(const u32* __restrict__ Ob,
    const int* __restrict__ bnd, float* __restrict__ psum, int N)
{
  __shared__ __align__(16) char SM[SMBYTES];
  pool_body(Ob, bnd, psum, N, blockIdx.x, SM);
}

__global__ __launch_bounds__(256) void fin_k(const float* __restrict__ ps0,
    const float* __restrict__ ps1, const int* __restrict__ bnd,
    const int* __restrict__ flag, void* __restrict__ out)
{
  fin_body(ps0, ps1, bnd, *flag, out, blockIdx.x);
}

extern "C" void kernel_launch(void* const* d_in, const int* in_sizes, int n_in,
                              void* d_out, int out_size, void* d_ws, size_t ws_size,
                              hipStream_t stream)
{
  const void* x    = d_in[0];
  const int* ei    = (const int*)d_in[1];
  const int* batch = (const int*)d_in[3];
  const void* W0  = d_in[4];
  const void* as0 = d_in[5];
  const void* ad0 = d_in[6];
  const void* b0  = d_in[7];
  const void* W1  = d_in[8];
  const void* as1 = d_in[9];
  const void* ad1 = d_in[10];
  const void* b1  = d_in[11];

  const int N  = in_sizes[0] / 128;   // 50000
  const int E  = in_sizes[1] / 2;     // 600000
  const int nbuck = (N + 255) >> 8;   // 196 (must be <= 256)

  char* ws = (char*)d_ws;
  size_t off = 0;
  auto al = [&](size_t bytes){ size_t o = off; off += (bytes + 255) & ~(size_t)255; return o; };
  u32*   Hb    = (u32*)(ws + al((size_t)N*32*4));          // 6.4 MB fp8 H (perm cols)
  u32*   Ob    = (u32*)(ws + al((size_t)N*64*4));          // 12.8 MB bf16 out (perm cols)
  float* As    = (float*)(ws + al((size_t)N*4));
  float* Ad    = (float*)(ws + al((size_t)N*4));
  u64*   breg  = (u64*)(ws + al((size_t)nbuck*BSTRIDE*8)); // 6.4 MB bucketed (dst,src)
  int*   csrc  = (int*)(ws + al((size_t)nbuck*BSTRIDE*4)); // 3.2 MB compact CSR srcs
  int*   rpd   = (int*)(ws + al((size_t)N*4));             // rowptr | deg<<20
  int*   bnd   = (int*)(ws + al(512));                     // graph starts [65] (full 512B!)
  // contiguous zero region: ps0 + ps1 + gcnt (one memset)
  const size_t zbytes = 2*64*128*4 + 256*4;
  char*  z0    = ws + al(zbytes);
  float* ps0   = (float*)z0;
  float* ps1   = ps0 + 8192;
  int*   gcnt  = (int*)(ps1 + 8192);
  int*   flag  = (int*)(ws + al(256));
  if (off > ws_size) return;

  hipMemsetAsync(z0, 0, zbytes, stream);

  const int gB   = (N/16 + 3) / 4;        // gemm tiles (782)
  const int aB   = (E + 2047) / 2048;     // part tiles (293)
  const int nvB16= (N*16 + 255) / 256;    // gath tiles (3125)
  const int pB   = (N + 127) / 128;       // pool tiles (391)

  MegaArgs A;
  A.x = (const u32*)x; A.ei = ei; A.batch = batch;
  A.W0 = W0; A.as0 = as0; A.ad0 = ad0; A.b0 = b0;
  A.W1 = W1; A.as1 = as1; A.ad1 = ad1; A.b1 = b1;
  A.Hb = Hb; A.Ob = Ob; A.As = As; A.Ad = Ad;
  A.breg = breg; A.csrc = csrc; A.rpd = rpd; A.bnd = bnd; A.gcnt = gcnt;
  A.ps0 = ps0; A.ps1 = ps1; A.out = d_out;
  A.N = N; A.E = E; A.nbuck = nbuck; A.gB = gB; A.aB = aB; A.nvB = nvB16; A.pB = pB;

  // Variant ladder: highest-occupancy spill-free variant wins.
  // (R6 lesson: an occupancy cap WITH spills is a 5x regression; R8 proved
  // the localSizeBytes guard correctly rejects spilling variants.)
  const void* kfun = (const void*)mega_k;
  hipFuncAttributes fa{};
  if (hipFuncGetAttributes(&fa, (const void*)mega_k4) == hipSuccess &&
      fa.localSizeBytes == 0)
    kfun = (const void*)mega_k4;
  else if (hipFuncGetAttributes(&fa, (const void*)mega_k3) == hipSuccess &&
           fa.localSizeBytes == 0)
    kfun = (const void*)mega_k3;

  int occ = 0;
  hipError_t qerr = hipOccupancyMaxActiveBlocksPerMultiprocessor(&occ, kfun, 256, 0);
  if (qerr == hipSuccess && occ >= 1){
    int grid = occ * 256;              // co-resident capacity (256 CUs)
    if (grid > 2048) grid = 2048;
    void* kargs[] = { (void*)&A };
    hipError_t err = hipLaunchCooperativeKernel(kfun,
        dim3(grid), dim3(256), kargs, 0, stream);
    if (err == hipSuccess) return;
  }

  // ---- fallback: proven round-5 dispatch sequence (same bodies) ----
  gemmdet0_k<<<gB + 1, 256, 0, stream>>>((const u32*)x, batch, bnd, flag,
      W0, as0, ad0, Hb, As, Ad, N, gB);
  part_k<<<aB, 256, 0, stream>>>(ei, E, nbuck, gcnt, breg);
  csr_k<<<nbuck, 256, 0, stream>>>(gcnt, breg, rpd, csrc, N);
  gath_k<true><<<nvB16, 256, 0, stream>>>(rpd, csrc, As, Ad, Hb, b0, flag, Ob, N);
  poolgemm1_k<<<pB + gB, 256, 0, stream>>>(Ob, bnd, ps0, pB,
      W1, as1, ad1, flag, Hb, As, Ad, N);
  gath_k<false><<<nvB16, 256, 0, stream>>>(rpd, csrc, As, Ad, Hb, b1, flag, Ob, N);
  pool2_k<<<pB, 256, 0, stream>>>(Ob, bnd, ps1, N);
  fin_k<<<32, 256, 0, stream>>>(ps0, ps1, bnd, flag, d_out);
}

// Round 10
// 184.474 us; speedup vs baseline: 2.4343x; 2.4280x over previous
//
#include <hip/hip_runtime.h>
#include <hip/hip_cooperative_groups.h>

typedef unsigned int u32;
typedef unsigned short u16;
typedef unsigned long long u64;

typedef short bf16x8 __attribute__((ext_vector_type(8)));
typedef float f32x4 __attribute__((ext_vector_type(4)));
typedef float f32x2 __attribute__((ext_vector_type(2)));

__device__ __forceinline__ float bl(u32 u){ return __uint_as_float(u << 16); }
__device__ __forceinline__ float bh(u32 u){ return __uint_as_float(u & 0xffff0000u); }
__device__ __forceinline__ float b16f(u16 r){ return __uint_as_float(((u32)r) << 16); }
__device__ __forceinline__ u16 f2b(float f){
  u32 u = __float_as_uint(f);
  u32 r = (u + 0x7fffu + ((u >> 16) & 1u)) >> 16;
  return (u16)r;
}
__device__ __forceinline__ u32 pk2(float a, float b){
  return (u32)f2b(a) | ((u32)f2b(b) << 16);
}
__device__ __forceinline__ void fma8(float* acc, float e2, uint2 h){
  f32x2 p0 = __builtin_amdgcn_cvt_pk_f32_fp8((int)h.x, 0);
  f32x2 p1 = __builtin_amdgcn_cvt_pk_f32_fp8((int)h.x, 1);
  f32x2 p2 = __builtin_amdgcn_cvt_pk_f32_fp8((int)h.y, 0);
  f32x2 p3 = __builtin_amdgcn_cvt_pk_f32_fp8((int)h.y, 1);
  acc[0]=fmaf(e2,p0.x,acc[0]); acc[1]=fmaf(e2,p0.y,acc[1]);
  acc[2]=fmaf(e2,p1.x,acc[2]); acc[3]=fmaf(e2,p1.y,acc[3]);
  acc[4]=fmaf(e2,p2.x,acc[4]); acc[5]=fmaf(e2,p2.y,acc[5]);
  acc[6]=fmaf(e2,p3.x,acc[6]); acc[7]=fmaf(e2,p3.y,acc[7]);
}

#define NEG_SLOPE 0.2f
#define BSTRIDE 4096   // slots per bucket region (max bucket ~3400 @ Poisson(3061))
#define SMBYTES 34816  // one shared buffer aliased by all phases (gemm Wt is largest)

// Stored-perm: pos p holds logical col c=(p&7)*16+(p>>3); fin unpermutes.
//
// R10 = EXACT R7 artifact (measured 182.7 us, best). R8 (gath fold) and R9
// (gemm acc-split + unroll caps, VGPR 172->100, grid 512->1024) BOTH landed
// at ~449 us despite opposite gath structures -> the regression tracks the
// register-diet/occupancy cluster, not gath. Do not cap gemm unrolls; do not
// fold gath shfls; do not raise the cooperative grid past 512.

// ---------------- device bodies -----------

// Per-block dtype vote over x[0..255] (bf16: low-16 exponent in [110,135]).
__device__ __forceinline__ int detect_body(const u32* __restrict__ x, char* SM){
  int* cnt_ = (int*)SM;
  if (threadIdx.x == 0) *cnt_ = 0;
  __syncthreads();
  u32 w = x[threadIdx.x];
  int e = (int)((w >> 7) & 0xFFu);
  if (e >= 110 && e <= 135) atomicAdd(cnt_, 1);
  __syncthreads();
  return (*cnt_ >= 128) ? 1 : 0;
}

__device__ __forceinline__ void bnd_body(const int* __restrict__ batch,
    int* __restrict__ bnd, int N)
{
  int g = threadIdx.x;
  if (g <= 64){
    int lo = 0, hi = N;
    while (lo < hi){ int mid = (lo + hi) >> 1; if (batch[mid] < g) lo = mid + 1; else hi = mid; }
    bnd[g] = lo;
  }
}

// CSR pass A: bucket-partition edges by dst>>8 into breg.
__device__ __forceinline__ void part_body(const int* __restrict__ ei, int E, int nbuck,
    int* __restrict__ gcnt, u64* __restrict__ breg, int job, char* SM)
{
  u64* stage = (u64*)SM;                 // [2048] @0      (16384 B)
  u32* hist  = (u32*)(SM + 16384);       // [256]
  u32* lscan = (u32*)(SM + 17408);       // [257]
  u32* gbase = (u32*)(SM + 18436);       // [256]
  u32* cur   = (u32*)(SM + 19460);       // [256]  end 20484 < 34816
  const int tid = threadIdx.x;
  __syncthreads();                       // SM alias safety
  hist[tid] = 0; cur[tid] = 0;
  __syncthreads();
  const int e0 = job * 2048;
  int src[8], dst[8];
  #pragma unroll
  for (int j = 0; j < 8; j++){
    int t = e0 + tid + j*256;
    if (t < E){
      src[j] = ei[t]; dst[j] = ei[E + t];
      atomicAdd(&hist[dst[j] >> 8], 1u);
    } else dst[j] = -1;
  }
  __syncthreads();
  const u32 v = hist[tid];
  lscan[tid] = v;
  __syncthreads();
  for (int off = 1; off < 256; off <<= 1){
    u32 add = (tid >= off) ? lscan[tid - off] : 0;
    __syncthreads();
    lscan[tid] += add;
    __syncthreads();
  }
  if (tid == 255) lscan[256] = lscan[255];   // block total
  u32 excl = lscan[tid] - v;
  __syncthreads();
  const u32 total = lscan[256];
  lscan[tid] = excl;                          // exclusive scan in place
  if (tid < nbuck && v > 0) gbase[tid] = (u32)atomicAdd(&gcnt[tid], (int)v);
  __syncthreads();
  #pragma unroll
  for (int j = 0; j < 8; j++){
    if (dst[j] >= 0){
      int b = dst[j] >> 8;
      u32 p = lscan[b] + atomicAdd(&cur[b], 1u);
      stage[p] = ((u64)(u32)dst[j] << 32) | (u32)src[j];
    }
  }
  __syncthreads();
  for (u32 i = tid; i < total; i += 256){
    u64 e = stage[i];
    int b = (int)(e >> 40);                   // (dst>>8)
    u32 r = i - lscan[b];
    breg[(long)b * BSTRIDE + gbase[b] + r] = e;
  }
}

// CSR pass B: per-bucket compact CSR. rpd = (base+excl) | (deg<<20).
__device__ __forceinline__ void csr_body(const int* __restrict__ gcnt,
    const u64* __restrict__ breg,
    int* __restrict__ rpd, int* __restrict__ csrc, int N, int job, char* SM)
{
  u32* dl = (u32*)SM;
  u32* rp = dl + 256;
  u32* cu = rp + 256;
  const int b = job, tid = threadIdx.x;
  const int n0 = b << 8;
  __syncthreads();                       // SM alias safety
  const int cntb = gcnt[b];
  dl[tid] = 0; cu[tid] = 0;
  __syncthreads();
  const u64* reg = breg + (long)b * BSTRIDE;
  for (int i = tid; i < cntb; i += 256)
    atomicAdd(&dl[(int)(reg[i] >> 32) - n0], 1u);
  __syncthreads();
  const u32 v = dl[tid];
  rp[tid] = v;
  __syncthreads();
  for (int off = 1; off < 256; off <<= 1){
    u32 add = (tid >= off) ? rp[tid - off] : 0;
    __syncthreads();
    rp[tid] += add;
    __syncthreads();
  }
  u32 excl = rp[tid] - v;
  __syncthreads();
  rp[tid] = excl;
  __syncthreads();
  int node = n0 + tid;
  if (node < N) rpd[node] = (int)(((u32)(b*BSTRIDE) + excl) | (v << 20));
  for (int i = tid; i < cntb; i += 256){
    u64 e = reg[i];
    int d = (int)(e >> 32) - n0;
    u32 pos = rp[d] + atomicAdd(&cu[d], 1u);
    csrc[(long)b*BSTRIDE + pos] = (int)(e & 0xffffffffULL);
  }
}

// MFMA GEMM body: Hb[N,128] (fp8 e4m3, stored-perm cols) = X @ W.
// R7 form: acc[8], full staging unrolls. (R9's acc-split + unroll caps were
// part of the 449-us regression cluster — keep this form.)
template<bool XEXT, bool KPERM>
__device__ __forceinline__ void gemm_body(int gb, int isbf,
    const void* __restrict__ Xv, const void* __restrict__ Wv,
    const void* __restrict__ av, const void* __restrict__ dv,
    u32* __restrict__ Hb, float* __restrict__ As, float* __restrict__ Ad, int N, char* SM)
{
  u16* Wt = (u16*)SM;              // [128*136] = 34816 B (pad 136: 2-way alias = free)
  const int tid = threadIdx.x;
  __syncthreads();                 // SM alias safety (prev job may still read)

  if (isbf){
    const u32* Wp = (const u32*)Wv;
    #pragma unroll
    for (int i = 0; i < 16; i++){
      int idx = tid + i*256;
      u32 p = Wp[idx];
      int k = idx >> 6, n2 = idx & 63;
      int pos = KPERM ? ((k & 15)*8 + (k >> 4)) : k;
      Wt[(2*n2)*136 + pos]   = (u16)(p & 0xffffu);
      Wt[(2*n2+1)*136 + pos] = (u16)(p >> 16);
    }
  } else {
    const float* Wf = (const float*)Wv;
    #pragma unroll
    for (int i = 0; i < 64; i++){
      int idx = tid + i*256;
      int k = idx >> 7, n = idx & 127;
      int pos = KPERM ? ((k & 15)*8 + (k >> 4)) : k;
      Wt[n*136 + pos] = f2b(Wf[idx]);
    }
  }
  __syncthreads();

  const int wv = tid >> 6, L = tid & 63;
  const int row0 = (gb*4 + wv) * 16;
  if (row0 >= N) return;
  const int nl = L & 15, quad = L >> 4;

  bf16x8 af[4];
  if (!XEXT || isbf){
    const uint4* Xr = (const uint4*)(((const u32*)Xv) + (long)row0*64);
    #pragma unroll
    for (int kb = 0; kb < 4; kb++)
      af[kb] = *(const bf16x8*)&Xr[nl*16 + kb*4 + quad];
  } else {
    const float* Xf = ((const float*)Xv) + (long)(row0 + nl)*128;
    #pragma unroll
    for (int kb = 0; kb < 4; kb++){
      const float4* p = (const float4*)(Xf + kb*32 + quad*8);
      float4 f0 = p[0], f1 = p[1];
      uint4 tmp = make_uint4(pk2(f0.x,f0.y), pk2(f0.z,f0.w), pk2(f1.x,f1.y), pk2(f1.z,f1.w));
      af[kb] = *(const bf16x8*)&tmp;
    }
  }

  f32x4 acc[8];
  #pragma unroll
  for (int nt = 0; nt < 8; nt++) acc[nt] = (f32x4){0.f,0.f,0.f,0.f};
  #pragma unroll
  for (int nt = 0; nt < 8; nt++){
    #pragma unroll
    for (int kb = 0; kb < 4; kb++){
      bf16x8 bf = *(const bf16x8*)&Wt[(nt*16 + nl)*136 + kb*32 + quad*8];
      acc[nt] = __builtin_amdgcn_mfma_f32_16x16x32_bf16(af[kb], bf, acc[nt], 0, 0, 0);
    }
  }

  float ps[4] = {0.f,0.f,0.f,0.f}, pd[4] = {0.f,0.f,0.f,0.f};
  #pragma unroll
  for (int nt = 0; nt < 8; nt++){
    int col = nt*16 + nl;
    float a_ = isbf ? b16f(((const u16*)av)[col]) : ((const float*)av)[col];
    float d_ = isbf ? b16f(((const u16*)dv)[col]) : ((const float*)dv)[col];
    #pragma unroll
    for (int r = 0; r < 4; r++){
      ps[r] = fmaf(acc[nt][r], a_, ps[r]);
      pd[r] = fmaf(acc[nt][r], d_, pd[r]);
    }
  }
  #pragma unroll
  for (int off = 1; off < 16; off <<= 1){
    #pragma unroll
    for (int r = 0; r < 4; r++){
      ps[r] += __shfl_xor(ps[r], off);
      pd[r] += __shfl_xor(pd[r], off);
    }
  }
  if (nl == 0){
    #pragma unroll
    for (int r = 0; r < 4; r++){
      As[row0 + quad*4 + r] = ps[r];
      Ad[row0 + quad*4 + r] = pd[r];
    }
  }

  #pragma unroll
  for (int r = 0; r < 4; r++){
    long row = row0 + quad*4 + r;
    int w0 = 0, w1 = 0;
    w0 = __builtin_amdgcn_cvt_pk_fp8_f32(acc[0][r], acc[1][r], w0, 0);
    w0 = __builtin_amdgcn_cvt_pk_fp8_f32(acc[2][r], acc[3][r], w0, 1);
    w1 = __builtin_amdgcn_cvt_pk_fp8_f32(acc[4][r], acc[5][r], w1, 0);
    w1 = __builtin_amdgcn_cvt_pk_fp8_f32(acc[6][r], acc[7][r], w1, 1);
    uint2 v = make_uint2((u32)w0, (u32)w1);
    *(uint2*)(Hb + row*32 + nl*2) = v;
  }
}

// Mean-pool partials. bnd[65] table in LDS -> no batch loads in hot loop.
__device__ __forceinline__ void pool_body(const u32* __restrict__ Ob,
    const int* __restrict__ bnd, float* __restrict__ psum, int N, int job, char* SM)
{
  int* bl_ = (int*)SM;                   // [65]
  const int tid = threadIdx.x;
  __syncthreads();                       // SM alias safety
  if (tid < 65) bl_[tid] = bnd[tid];
  __syncthreads();
  const int wv = tid >> 6, lane = tid & 63;
  const int start = job * 128;
  const int end = min(start + 128, N);
  int node = start + wv;
  if (node >= end) return;
  // largest g with bl_[g] <= node  (bl_[64]=N > node)
  int lo = 0, hi = 64;
  while (lo + 1 < hi){ int mid = (lo + hi) >> 1; if (bl_[mid] <= node) lo = mid; else hi = mid; }
  int cur = lo, nextb = bl_[cur + 1];
  float2 acc = make_float2(0.f, 0.f);
  const u32* __restrict__ ob = Ob + lane;
  for (int j = 0; j < 32; j += 4){
    int n0 = node + 4*j, n1 = n0 + 4, n2 = n0 + 8, n3 = n0 + 12;
    u32 p0 = 0, p1 = 0, p2 = 0, p3 = 0;
    if (n0 < end) p0 = ob[(long)n0*64];
    if (n1 < end) p1 = ob[(long)n1*64];
    if (n2 < end) p2 = ob[(long)n2*64];
    if (n3 < end) p3 = ob[(long)n3*64];
    #define PSTEP(nd, pv) \
      if (nd < end){ \
        while (nd >= nextb){ \
          atomicAdd(&psum[cur*128 + lane*2],     acc.x); \
          atomicAdd(&psum[cur*128 + lane*2 + 1], acc.y); \
          acc = make_float2(0.f, 0.f); \
          cur++; nextb = bl_[cur + 1]; \
        } \
        acc.x += bl(pv); acc.y += bh(pv); \
      }
    PSTEP(n0, p0) PSTEP(n1, p1) PSTEP(n2, p2) PSTEP(n3, p3)
    #undef PSTEP
  }
  atomicAdd(&psum[cur*128 + lane*2],     acc.x);
  atomicAdd(&psum[cur*128 + lane*2 + 1], acc.y);
}

// Fused per-node softmax-aggregate over fp8 Hb, 16 lanes/node, full-16 MLP.
// R7 batched form: s[16] -> one wait -> 16 loads in flight. Do not fold
// (R8's folded form serialized 16 bpermute round-trips).
template<bool RELU>
__device__ __forceinline__ void gath_body(const int* __restrict__ rpd,
    const int* __restrict__ csrc,
    const float* __restrict__ As, const float* __restrict__ Ad,
    const u32* __restrict__ Hb, const void* __restrict__ bv, int isbf,
    u32* __restrict__ Ob, int N, int job)
{
  long t = (long)job*256 + threadIdx.x;
  int node = (int)(t >> 4), q = (int)(t & 15);
  if (node >= N) return;
  const int base = threadIdx.x & 48;
  const float ad = Ad[node];
  const u32 pk = (u32)rpd[node];
  const int dg = (int)(pk >> 20);
  const int* row = csrc + (pk & 0xFFFFFu);
  float l = As[node] + ad;
  l = l > 0.f ? l : NEG_SLOPE * l;
  float e = __expf(l);
  float acc[8];
  {
    uint2 hv = ((const uint2*)(Hb + (long)node*32))[q];
    f32x2 p0 = __builtin_amdgcn_cvt_pk_f32_fp8((int)hv.x, 0);
    f32x2 p1 = __builtin_amdgcn_cvt_pk_f32_fp8((int)hv.x, 1);
    f32x2 p2 = __builtin_amdgcn_cvt_pk_f32_fp8((int)hv.y, 0);
    f32x2 p3 = __builtin_amdgcn_cvt_pk_f32_fp8((int)hv.y, 1);
    acc[0]=e*p0.x; acc[1]=e*p0.y; acc[2]=e*p1.x; acc[3]=e*p1.y;
    acc[4]=e*p2.x; acc[5]=e*p2.y; acc[6]=e*p3.x; acc[7]=e*p3.y;
  }
  float den = e;
  for (int jb = 0; jb < dg; jb += 16){
    int m = dg - jb; if (m > 16) m = 16;
    int sj = node;                         // tail lanes: e=0 (no-op), s=node (safe addr)
    if (q < m) sj = row[jb + q];
    float asv = As[sj];                    // gather issued early, overlaps below
    int s[16];
    #pragma unroll
    for (int i = 0; i < 16; i++) s[i] = __shfl(sj, base + i);
    uint2 h[16];
    #pragma unroll
    for (int i = 0; i < 16; i++) h[i] = ((const uint2*)(Hb + (long)s[i]*32))[q];
    float evq = 0.f;
    if (q < m){
      float l2 = asv + ad;
      l2 = l2 > 0.f ? l2 : NEG_SLOPE * l2;
      evq = __expf(l2);
    }
    float ev[16];
    #pragma unroll
    for (int i = 0; i < 16; i++) ev[i] = __shfl(evq, base + i);
    float dsum = 0.f;
    #pragma unroll
    for (int i = 0; i < 16; i++) dsum += ev[i];
    den += dsum;
    #pragma unroll
    for (int i = 0; i < 16; i++) fma8(acc, ev[i], h[i]);
  }
  float inv = 1.f / den;
  float b[8];
  if (isbf){
    const u16* bp = (const u16*)bv;
    #pragma unroll
    for (int i = 0; i < 8; i++) b[i] = b16f(bp[i*16 + q]);
  } else {
    const float* bp = (const float*)bv;
    #pragma unroll
    for (int i = 0; i < 8; i++) b[i] = bp[i*16 + q];
  }
  float o[8];
  #pragma unroll
  for (int i = 0; i < 8; i++){
    o[i] = fmaf(acc[i], inv, b[i]);
    if (RELU) o[i] = fmaxf(o[i], 0.f);
  }
  uint4 w = make_uint4(pk2(o[0],o[1]), pk2(o[2],o[3]), pk2(o[4],o[5]), pk2(o[6],o[7]));
  *(uint4*)&Ob[(long)node*64 + q*4] = w;
}

// Per-graph mean (counts from bnd), unpermute stored cols, store.
__device__ __forceinline__ void fin_body(const float* __restrict__ ps0,
    const float* __restrict__ ps1, const int* __restrict__ bnd,
    int isbf, void* __restrict__ out, int job)
{
  int t = job*256 + threadIdx.x;
  if (t >= 8192) return;
  int g = t >> 7, pos = t & 127;
  int c = ((pos & 7) << 4) + (pos >> 3);
  int cc = bnd[g+1] - bnd[g];
  float cf = (float)(cc < 1 ? 1 : cc);
  float v0 = ps0[t] / cf, v1 = ps1[t] / cf;
  if (isbf){
    u16* o = (u16*)out;
    o[g*128 + c] = f2b(v0); o[8192 + g*128 + c] = f2b(v1);
  } else {
    float* o = (float*)out;
    o[g*128 + c] = v0; o[8192 + g*128 + c] = v1;
  }
}

// ---------------- cooperative megakernel: whole pipeline, 1 dispatch ----------

struct MegaArgs {
  const u32* x; const int* ei; const int* batch;
  const void *W0, *as0, *ad0, *b0, *W1, *as1, *ad1, *b1;
  u32 *Hb, *Ob; float *As, *Ad;
  u64* breg; int *csrc, *rpd, *bnd, *gcnt;
  float *ps0, *ps1; void* out;
  int N, E, nbuck, gB, aB, nvB, pB;
};

__global__ __launch_bounds__(256) void mega_k(MegaArgs a)
{
  __shared__ __align__(16) char SM[SMBYTES];
  cooperative_groups::grid_group grid = cooperative_groups::this_grid();
  const int nb = (int)gridDim.x;
  const int isbf = detect_body(a.x, SM);

  // P0: gemm0 tiles [0,gB), bnd job gB, part tiles (gB, gB+aB]
  for (int j = blockIdx.x; j < a.gB + 1 + a.aB; j += nb){
    if (j < a.gB)       gemm_body<true,false>(j, isbf, a.x, a.W0, a.as0, a.ad0, a.Hb, a.As, a.Ad, a.N, SM);
    else if (j == a.gB) bnd_body(a.batch, a.bnd, a.N);
    else                part_body(a.ei, a.E, a.nbuck, a.gcnt, a.breg, j - a.gB - 1, SM);
  }
  grid.sync();
  // P1: csr (needs all part buckets)
  for (int j = blockIdx.x; j < a.nbuck; j += nb)
    csr_body(a.gcnt, a.breg, a.rpd, a.csrc, a.N, j, SM);
  grid.sync();
  // P2: layer-0 gather (+relu)
  for (int j = blockIdx.x; j < a.nvB; j += nb)
    gath_body<true>(a.rpd, a.csrc, a.As, a.Ad, a.Hb, a.b0, isbf, a.Ob, a.N, j);
  grid.sync();
  // P3: pool0 + gemm1 (independent jobs)
  for (int j = blockIdx.x; j < a.pB + a.gB; j += nb){
    if (j < a.pB) pool_body(a.Ob, a.bnd, a.ps0, a.N, j, SM);
    else          gemm_body<false,true>(j - a.pB, isbf, a.Ob, a.W1, a.as1, a.ad1, a.Hb, a.As, a.Ad, a.N, SM);
  }
  grid.sync();
  // P4: layer-1 gather
  for (int j = blockIdx.x; j < a.nvB; j += nb)
    gath_body<false>(a.rpd, a.csrc, a.As, a.Ad, a.Hb, a.b1, isbf, a.Ob, a.N, j);
  grid.sync();
  // P5: pool1
  for (int j = blockIdx.x; j < a.pB; j += nb)
    pool_body(a.Ob, a.bnd, a.ps1, a.N, j, SM);
  grid.sync();
  // P6: fin
  for (int j = blockIdx.x; j < 32; j += nb)
    fin_body(a.ps0, a.ps1, a.bnd, isbf, a.out, j);
}

// ---------------- fallback standalone kernels (round-5 proven sequence) ------

__global__ __launch_bounds__(256) void gemmdet0_k(
    const u32* __restrict__ x, const int* __restrict__ batch, int* __restrict__ bnd,
    int* __restrict__ flag,
    const void* __restrict__ W0, const void* __restrict__ as0, const void* __restrict__ ad0,
    u32* __restrict__ Hb, float* __restrict__ As, float* __restrict__ Ad, int N, int gB)
{
  __shared__ __align__(16) char SM[SMBYTES];
  if ((int)blockIdx.x == gB){ bnd_body(batch, bnd, N); return; }
  int isbf = detect_body(x, SM);
  if (blockIdx.x == 0 && threadIdx.x == 0) *flag = isbf;
  gemm_body<true, false>(blockIdx.x, isbf, x, W0, as0, ad0, Hb, As, Ad, N, SM);
}

__global__ __launch_bounds__(256) void part_k(const int* __restrict__ ei, int E, int nbuck,
    int* __restrict__ gcnt, u64* __restrict__ breg)
{
  __shared__ __align__(16) char SM[SMBYTES];
  part_body(ei, E, nbuck, gcnt, breg, blockIdx.x, SM);
}

__global__ __launch_bounds__(256) void csr_k(const int* __restrict__ gcnt,
    const u64* __restrict__ breg,
    int* __restrict__ rpd, int* __restrict__ csrc, int N)
{
  __shared__ __align__(16) char SM[SMBYTES];
  csr_body(gcnt, breg, rpd, csrc, N, blockIdx.x, SM);
}

template<bool RELU>
__global__ __launch_bounds__(256) void gath_k(const int* __restrict__ rpd,
    const int* __restrict__ csrc,
    const float* __restrict__ As, const float* __restrict__ Ad,
    const u32* __restrict__ Hb, const void* __restrict__ bv, const int* __restrict__ flag,
    u32* __restrict__ Ob, int N)
{
  gath_body<RELU>(rpd, csrc, As, Ad, Hb, bv, *flag, Ob, N, blockIdx.x);
}

__global__ __launch_bounds__(256) void poolgemm1_k(
    const u32* __restrict__ Ob, const int* __restrict__ bnd, float* __restrict__ ps0, int pB,
    const void* __restrict__ W1, const void* __restrict__ as1, const void* __restrict__ ad1,
    const int* __restrict__ flag,
    u32* __restrict__ Hb, float* __restrict__ As, float* __restrict__ Ad, int N)
{
  __shared__ __align__(16) char SM[SMBYTES];
  if ((int)blockIdx.x < pB){ pool_body(Ob, bnd, ps0, N, blockIdx.x, SM); return; }
  gemm_body<false, true>(blockIdx.x - pB, *flag, Ob, W1, as1, ad1, Hb, As, Ad, N, SM);
}

__global__ __launch_bounds__(256) void pool2_k(const u32* __restrict__ Ob,
    const int* __restrict__ bnd, float* __restrict__ psum, int N)
{
  __shared__ __align__(16) char SM[SMBYTES];
  pool_body(Ob, bnd, psum, N, blockIdx.x, SM);
}

__global__ __launch_bounds__(256) void fin_k(const float* __restrict__ ps0,
    const float* __restrict__ ps1, const int* __restrict__ bnd,
    const int* __restrict__ flag, void* __restrict__ out)
{
  fin_body(ps0, ps1, bnd, *flag, out, blockIdx.x);
}

extern "C" void kernel_launch(void* const* d_in, const int* in_sizes, int n_in,
                              void* d_out, int out_size, void* d_ws, size_t ws_size,
                              hipStream_t stream)
{
  const void* x    = d_in[0];
  const int* ei    = (const int*)d_in[1];
  const int* batch = (const int*)d_in[3];
  const void* W0  = d_in[4];
  const void* as0 = d_in[5];
  const void* ad0 = d_in[6];
  const void* b0  = d_in[7];
  const void* W1  = d_in[8];
  const void* as1 = d_in[9];
  const void* ad1 = d_in[10];
  const void* b1  = d_in[11];

  const int N  = in_sizes[0] / 128;   // 50000
  const int E  = in_sizes[1] / 2;     // 600000
  const int nbuck = (N + 255) >> 8;   // 196 (must be <= 256)

  char* ws = (char*)d_ws;
  size_t off = 0;
  auto al = [&](size_t bytes){ size_t o = off; off += (bytes + 255) & ~(size_t)255; return o; };
  u32*   Hb    = (u32*)(ws + al((size_t)N*32*4));          // 6.4 MB fp8 H (perm cols)
  u32*   Ob    = (u32*)(ws + al((size_t)N*64*4));          // 12.8 MB bf16 out (perm cols)
  float* As    = (float*)(ws + al((size_t)N*4));
  float* Ad    = (float*)(ws + al((size_t)N*4));
  u64*   breg  = (u64*)(ws + al((size_t)nbuck*BSTRIDE*8)); // 6.4 MB bucketed (dst,src)
  int*   csrc  = (int*)(ws + al((size_t)nbuck*BSTRIDE*4)); // 3.2 MB compact CSR srcs
  int*   rpd   = (int*)(ws + al((size_t)N*4));             // rowptr | deg<<20
  int*   bnd   = (int*)(ws + al(512));                     // graph starts [65] (full 512B!)
  // contiguous zero region: ps0 + ps1 + gcnt (one memset)
  const size_t zbytes = 2*64*128*4 + 256*4;
  char*  z0    = ws + al(zbytes);
  float* ps0   = (float*)z0;
  float* ps1   = ps0 + 8192;
  int*   gcnt  = (int*)(ps1 + 8192);
  int*   flag  = (int*)(ws + al(256));
  if (off > ws_size) return;

  hipMemsetAsync(z0, 0, zbytes, stream);

  const int gB   = (N/16 + 3) / 4;        // gemm tiles (782)
  const int aB   = (E + 2047) / 2048;     // part tiles (293)
  const int nvB16= (N*16 + 255) / 256;    // gath tiles (3125)
  const int pB   = (N + 127) / 128;       // pool tiles (391)

  MegaArgs A;
  A.x = (const u32*)x; A.ei = ei; A.batch = batch;
  A.W0 = W0; A.as0 = as0; A.ad0 = ad0; A.b0 = b0;
  A.W1 = W1; A.as1 = as1; A.ad1 = ad1; A.b1 = b1;
  A.Hb = Hb; A.Ob = Ob; A.As = As; A.Ad = Ad;
  A.breg = breg; A.csrc = csrc; A.rpd = rpd; A.bnd = bnd; A.gcnt = gcnt;
  A.ps0 = ps0; A.ps1 = ps1; A.out = d_out;
  A.N = N; A.E = E; A.nbuck = nbuck; A.gB = gB; A.aB = aB; A.nvB = nvB16; A.pB = pB;

  int occ = 0;
  hipError_t qerr = hipOccupancyMaxActiveBlocksPerMultiprocessor(
      &occ, (const void*)mega_k, 256, 0);
  if (qerr == hipSuccess && occ >= 1){
    int grid = occ * 256;              // co-resident capacity (256 CUs)
    if (grid > 512) grid = 512;        // R8/R9: grid 1024 regime measured 2.5x
                                       // slower than R7's 512 — never exceed it.
    void* kargs[] = { (void*)&A };
    hipError_t err = hipLaunchCooperativeKernel((const void*)mega_k,
        dim3(grid), dim3(256), kargs, 0, stream);
    if (err == hipSuccess) return;
  }

  // ---- fallback: proven round-5 dispatch sequence (same bodies) ----
  gemmdet0_k<<<gB + 1, 256, 0, stream>>>((const u32*)x, batch, bnd, flag,
      W0, as0, ad0, Hb, As, Ad, N, gB);
  part_k<<<aB, 256, 0, stream>>>(ei, E, nbuck, gcnt, breg);
  csr_k<<<nbuck, 256, 0, stream>>>(gcnt, breg, rpd, csrc, N);
  gath_k<true><<<nvB16, 256, 0, stream>>>(rpd, csrc, As, Ad, Hb, b0, flag, Ob, N);
  poolgemm1_k<<<pB + gB, 256, 0, stream>>>(Ob, bnd, ps0, pB,
      W1, as1, ad1, flag, Hb, As, Ad, N);
  gath_k<false><<<nvB16, 256, 0, stream>>>(rpd, csrc, As, Ad, Hb, b1, flag, Ob, N);
  pool2_k<<<pB, 256, 0, stream>>>(Ob, bnd, ps1, N);
  fin_k<<<32, 256, 0, stream>>>(ps0, ps1, bnd, flag, d_out);
}

// Round 11
// 181.522 us; speedup vs baseline: 2.4739x; 1.0163x over previous
//
#include <hip/hip_runtime.h>
#include <hip/hip_cooperative_groups.h>

typedef unsigned int u32;
typedef unsigned short u16;
typedef unsigned long long u64;

typedef short bf16x8 __attribute__((ext_vector_type(8)));
typedef float f32x4 __attribute__((ext_vector_type(4)));
typedef float f32x2 __attribute__((ext_vector_type(2)));

__device__ __forceinline__ float bl(u32 u){ return __uint_as_float(u << 16); }
__device__ __forceinline__ float bh(u32 u){ return __uint_as_float(u & 0xffff0000u); }
__device__ __forceinline__ float b16f(u16 r){ return __uint_as_float(((u32)r) << 16); }
__device__ __forceinline__ u16 f2b(float f){
  u32 u = __float_as_uint(f);
  u32 r = (u + 0x7fffu + ((u >> 16) & 1u)) >> 16;
  return (u16)r;
}
__device__ __forceinline__ u32 pk2(float a, float b){
  return (u32)f2b(a) | ((u32)f2b(b) << 16);
}
__device__ __forceinline__ void fma8(float* acc, float e2, uint2 h){
  f32x2 p0 = __builtin_amdgcn_cvt_pk_f32_fp8((int)h.x, 0);
  f32x2 p1 = __builtin_amdgcn_cvt_pk_f32_fp8((int)h.x, 1);
  f32x2 p2 = __builtin_amdgcn_cvt_pk_f32_fp8((int)h.y, 0);
  f32x2 p3 = __builtin_amdgcn_cvt_pk_f32_fp8((int)h.y, 1);
  acc[0]=fmaf(e2,p0.x,acc[0]); acc[1]=fmaf(e2,p0.y,acc[1]);
  acc[2]=fmaf(e2,p1.x,acc[2]); acc[3]=fmaf(e2,p1.y,acc[3]);
  acc[4]=fmaf(e2,p2.x,acc[4]); acc[5]=fmaf(e2,p2.y,acc[5]);
  acc[6]=fmaf(e2,p3.x,acc[6]); acc[7]=fmaf(e2,p3.y,acc[7]);
}

#define NEG_SLOPE 0.2f
#define BSTRIDE 4096   // slots per bucket region (max bucket ~3400 @ Poisson(3061))
#define SMBYTES 34816  // one shared buffer aliased by all phases (gemm Wt is largest)

// Stored-perm: pos p holds logical col c=(p&7)*16+(p>>3); fin unpermutes.
//
// R11 = R10 (the reproduced 182.7/184.5-us best) + split CSR: each node's
// first <=16 srcs live at csrc16[node*16+li] so the gather issues them in
// PARALLEL with rpd[node] (removes one L2 round-trip from the per-node
// serial chain for ~90% of nodes at Poisson(12)). Overflow (li>=16) stays
// in the bucket region at base+excl+li. Locked invariants from R6-R10:
// no gemm unroll caps, no gath shfl folding, cooperative grid <= 512.

// ---------------- device bodies -----------

// Per-block dtype vote over x[0..255] (bf16: low-16 exponent in [110,135]).
__device__ __forceinline__ int detect_body(const u32* __restrict__ x, char* SM){
  int* cnt_ = (int*)SM;
  if (threadIdx.x == 0) *cnt_ = 0;
  __syncthreads();
  u32 w = x[threadIdx.x];
  int e = (int)((w >> 7) & 0xFFu);
  if (e >= 110 && e <= 135) atomicAdd(cnt_, 1);
  __syncthreads();
  return (*cnt_ >= 128) ? 1 : 0;
}

__device__ __forceinline__ void bnd_body(const int* __restrict__ batch,
    int* __restrict__ bnd, int N)
{
  int g = threadIdx.x;
  if (g <= 64){
    int lo = 0, hi = N;
    while (lo < hi){ int mid = (lo + hi) >> 1; if (batch[mid] < g) lo = mid + 1; else hi = mid; }
    bnd[g] = lo;
  }
}

// CSR pass A: bucket-partition edges by dst>>8 into breg.
__device__ __forceinline__ void part_body(const int* __restrict__ ei, int E, int nbuck,
    int* __restrict__ gcnt, u64* __restrict__ breg, int job, char* SM)
{
  u64* stage = (u64*)SM;                 // [2048] @0      (16384 B)
  u32* hist  = (u32*)(SM + 16384);       // [256]
  u32* lscan = (u32*)(SM + 17408);       // [257]
  u32* gbase = (u32*)(SM + 18436);       // [256]
  u32* cur   = (u32*)(SM + 19460);       // [256]  end 20484 < 34816
  const int tid = threadIdx.x;
  __syncthreads();                       // SM alias safety
  hist[tid] = 0; cur[tid] = 0;
  __syncthreads();
  const int e0 = job * 2048;
  int src[8], dst[8];
  #pragma unroll
  for (int j = 0; j < 8; j++){
    int t = e0 + tid + j*256;
    if (t < E){
      src[j] = ei[t]; dst[j] = ei[E + t];
      atomicAdd(&hist[dst[j] >> 8], 1u);
    } else dst[j] = -1;
  }
  __syncthreads();
  const u32 v = hist[tid];
  lscan[tid] = v;
  __syncthreads();
  for (int off = 1; off < 256; off <<= 1){
    u32 add = (tid >= off) ? lscan[tid - off] : 0;
    __syncthreads();
    lscan[tid] += add;
    __syncthreads();
  }
  if (tid == 255) lscan[256] = lscan[255];   // block total
  u32 excl = lscan[tid] - v;
  __syncthreads();
  const u32 total = lscan[256];
  lscan[tid] = excl;                          // exclusive scan in place
  if (tid < nbuck && v > 0) gbase[tid] = (u32)atomicAdd(&gcnt[tid], (int)v);
  __syncthreads();
  #pragma unroll
  for (int j = 0; j < 8; j++){
    if (dst[j] >= 0){
      int b = dst[j] >> 8;
      u32 p = lscan[b] + atomicAdd(&cur[b], 1u);
      stage[p] = ((u64)(u32)dst[j] << 32) | (u32)src[j];
    }
  }
  __syncthreads();
  for (u32 i = tid; i < total; i += 256){
    u64 e = stage[i];
    int b = (int)(e >> 40);                   // (dst>>8)
    u32 r = i - lscan[b];
    breg[(long)b * BSTRIDE + gbase[b] + r] = e;
  }
}

// CSR pass B: per-bucket compact CSR. rpd = (base+excl) | (deg<<20).
// R11: first <=16 srcs of each node -> csrc16[node*16+li] (fixed slot);
// overflow li>=16 -> bucket region at base+excl+li (same as old pos).
__device__ __forceinline__ void csr_body(const int* __restrict__ gcnt,
    const u64* __restrict__ breg,
    int* __restrict__ rpd, int* __restrict__ csrc, int* __restrict__ csrc16,
    int N, int job, char* SM)
{
  u32* dl = (u32*)SM;
  u32* rp = dl + 256;
  u32* cu = rp + 256;
  const int b = job, tid = threadIdx.x;
  const int n0 = b << 8;
  __syncthreads();                       // SM alias safety
  const int cntb = gcnt[b];
  dl[tid] = 0; cu[tid] = 0;
  __syncthreads();
  const u64* reg = breg + (long)b * BSTRIDE;
  for (int i = tid; i < cntb; i += 256)
    atomicAdd(&dl[(int)(reg[i] >> 32) - n0], 1u);
  __syncthreads();
  const u32 v = dl[tid];
  rp[tid] = v;
  __syncthreads();
  for (int off = 1; off < 256; off <<= 1){
    u32 add = (tid >= off) ? rp[tid - off] : 0;
    __syncthreads();
    rp[tid] += add;
    __syncthreads();
  }
  u32 excl = rp[tid] - v;
  __syncthreads();
  rp[tid] = excl;
  __syncthreads();
  int node = n0 + tid;
  if (node < N) rpd[node] = (int)(((u32)(b*BSTRIDE) + excl) | (v << 20));
  for (int i = tid; i < cntb; i += 256){
    u64 e = reg[i];
    int d = (int)(e >> 32) - n0;
    u32 li = atomicAdd(&cu[d], 1u);          // per-node local edge index
    int s = (int)(e & 0xffffffffULL);
    if (li < 16) csrc16[((long)(n0 + d))*16 + li] = s;
    else         csrc[(long)b*BSTRIDE + rp[d] + li] = s;
  }
}

// MFMA GEMM body: Hb[N,128] (fp8 e4m3, stored-perm cols) = X @ W.
// R7 form: acc[8], full staging unrolls (R9's diet was a regression).
template<bool XEXT, bool KPERM>
__device__ __forceinline__ void gemm_body(int gb, int isbf,
    const void* __restrict__ Xv, const void* __restrict__ Wv,
    const void* __restrict__ av, const void* __restrict__ dv,
    u32* __restrict__ Hb, float* __restrict__ As, float* __restrict__ Ad, int N, char* SM)
{
  u16* Wt = (u16*)SM;              // [128*136] = 34816 B (pad 136: 2-way alias = free)
  const int tid = threadIdx.x;
  __syncthreads();                 // SM alias safety (prev job may still read)

  if (isbf){
    const u32* Wp = (const u32*)Wv;
    #pragma unroll
    for (int i = 0; i < 16; i++){
      int idx = tid + i*256;
      u32 p = Wp[idx];
      int k = idx >> 6, n2 = idx & 63;
      int pos = KPERM ? ((k & 15)*8 + (k >> 4)) : k;
      Wt[(2*n2)*136 + pos]   = (u16)(p & 0xffffu);
      Wt[(2*n2+1)*136 + pos] = (u16)(p >> 16);
    }
  } else {
    const float* Wf = (const float*)Wv;
    #pragma unroll
    for (int i = 0; i < 64; i++){
      int idx = tid + i*256;
      int k = idx >> 7, n = idx & 127;
      int pos = KPERM ? ((k & 15)*8 + (k >> 4)) : k;
      Wt[n*136 + pos] = f2b(Wf[idx]);
    }
  }
  __syncthreads();

  const int wv = tid >> 6, L = tid & 63;
  const int row0 = (gb*4 + wv) * 16;
  if (row0 >= N) return;
  const int nl = L & 15, quad = L >> 4;

  bf16x8 af[4];
  if (!XEXT || isbf){
    const uint4* Xr = (const uint4*)(((const u32*)Xv) + (long)row0*64);
    #pragma unroll
    for (int kb = 0; kb < 4; kb++)
      af[kb] = *(const bf16x8*)&Xr[nl*16 + kb*4 + quad];
  } else {
    const float* Xf = ((const float*)Xv) + (long)(row0 + nl)*128;
    #pragma unroll
    for (int kb = 0; kb < 4; kb++){
      const float4* p = (const float4*)(Xf + kb*32 + quad*8);
      float4 f0 = p[0], f1 = p[1];
      uint4 tmp = make_uint4(pk2(f0.x,f0.y), pk2(f0.z,f0.w), pk2(f1.x,f1.y), pk2(f1.z,f1.w));
      af[kb] = *(const bf16x8*)&tmp;
    }
  }

  f32x4 acc[8];
  #pragma unroll
  for (int nt = 0; nt < 8; nt++) acc[nt] = (f32x4){0.f,0.f,0.f,0.f};
  #pragma unroll
  for (int nt = 0; nt < 8; nt++){
    #pragma unroll
    for (int kb = 0; kb < 4; kb++){
      bf16x8 bf = *(const bf16x8*)&Wt[(nt*16 + nl)*136 + kb*32 + quad*8];
      acc[nt] = __builtin_amdgcn_mfma_f32_16x16x32_bf16(af[kb], bf, acc[nt], 0, 0, 0);
    }
  }

  float ps[4] = {0.f,0.f,0.f,0.f}, pd[4] = {0.f,0.f,0.f,0.f};
  #pragma unroll
  for (int nt = 0; nt < 8; nt++){
    int col = nt*16 + nl;
    float a_ = isbf ? b16f(((const u16*)av)[col]) : ((const float*)av)[col];
    float d_ = isbf ? b16f(((const u16*)dv)[col]) : ((const float*)dv)[col];
    #pragma unroll
    for (int r = 0; r < 4; r++){
      ps[r] = fmaf(acc[nt][r], a_, ps[r]);
      pd[r] = fmaf(acc[nt][r], d_, pd[r]);
    }
  }
  #pragma unroll
  for (int off = 1; off < 16; off <<= 1){
    #pragma unroll
    for (int r = 0; r < 4; r++){
      ps[r] += __shfl_xor(ps[r], off);
      pd[r] += __shfl_xor(pd[r], off);
    }
  }
  if (nl == 0){
    #pragma unroll
    for (int r = 0; r < 4; r++){
      As[row0 + quad*4 + r] = ps[r];
      Ad[row0 + quad*4 + r] = pd[r];
    }
  }

  #pragma unroll
  for (int r = 0; r < 4; r++){
    long row = row0 + quad*4 + r;
    int w0 = 0, w1 = 0;
    w0 = __builtin_amdgcn_cvt_pk_fp8_f32(acc[0][r], acc[1][r], w0, 0);
    w0 = __builtin_amdgcn_cvt_pk_fp8_f32(acc[2][r], acc[3][r], w0, 1);
    w1 = __builtin_amdgcn_cvt_pk_fp8_f32(acc[4][r], acc[5][r], w1, 0);
    w1 = __builtin_amdgcn_cvt_pk_fp8_f32(acc[6][r], acc[7][r], w1, 1);
    uint2 v = make_uint2((u32)w0, (u32)w1);
    *(uint2*)(Hb + row*32 + nl*2) = v;
  }
}

// Mean-pool partials. bnd[65] table in LDS -> no batch loads in hot loop.
__device__ __forceinline__ void pool_body(const u32* __restrict__ Ob,
    const int* __restrict__ bnd, float* __restrict__ psum, int N, int job, char* SM)
{
  int* bl_ = (int*)SM;                   // [65]
  const int tid = threadIdx.x;
  __syncthreads();                       // SM alias safety
  if (tid < 65) bl_[tid] = bnd[tid];
  __syncthreads();
  const int wv = tid >> 6, lane = tid & 63;
  const int start = job * 128;
  const int end = min(start + 128, N);
  int node = start + wv;
  if (node >= end) return;
  // largest g with bl_[g] <= node  (bl_[64]=N > node)
  int lo = 0, hi = 64;
  while (lo + 1 < hi){ int mid = (lo + hi) >> 1; if (bl_[mid] <= node) lo = mid; else hi = mid; }
  int cur = lo, nextb = bl_[cur + 1];
  float2 acc = make_float2(0.f, 0.f);
  const u32* __restrict__ ob = Ob + lane;
  for (int j = 0; j < 32; j += 4){
    int n0 = node + 4*j, n1 = n0 + 4, n2 = n0 + 8, n3 = n0 + 12;
    u32 p0 = 0, p1 = 0, p2 = 0, p3 = 0;
    if (n0 < end) p0 = ob[(long)n0*64];
    if (n1 < end) p1 = ob[(long)n1*64];
    if (n2 < end) p2 = ob[(long)n2*64];
    if (n3 < end) p3 = ob[(long)n3*64];
    #define PSTEP(nd, pv) \
      if (nd < end){ \
        while (nd >= nextb){ \
          atomicAdd(&psum[cur*128 + lane*2],     acc.x); \
          atomicAdd(&psum[cur*128 + lane*2 + 1], acc.y); \
          acc = make_float2(0.f, 0.f); \
          cur++; nextb = bl_[cur + 1]; \
        } \
        acc.x += bl(pv); acc.y += bh(pv); \
      }
    PSTEP(n0, p0) PSTEP(n1, p1) PSTEP(n2, p2) PSTEP(n3, p3)
    #undef PSTEP
  }
  atomicAdd(&psum[cur*128 + lane*2],     acc.x);
  atomicAdd(&psum[cur*128 + lane*2 + 1], acc.y);
}

// Fused per-node softmax-aggregate over fp8 Hb, 16 lanes/node, full-16 MLP.
// R7 batched shfl/load structure (do not fold — R8 lesson). R11: first-tile
// src comes from csrc16[node*16+q], ISSUED IN PARALLEL with rpd[node]
// (value only consumed when q < m, so stale slots are harmless).
template<bool RELU>
__device__ __forceinline__ void gath_body(const int* __restrict__ rpd,
    const int* __restrict__ csrc, const int* __restrict__ csrc16,
    const float* __restrict__ As, const float* __restrict__ Ad,
    const u32* __restrict__ Hb, const void* __restrict__ bv, int isbf,
    u32* __restrict__ Ob, int N, int job)
{
  long t = (long)job*256 + threadIdx.x;
  int node = (int)(t >> 4), q = (int)(t & 15);
  if (node >= N) return;
  const int base = threadIdx.x & 48;
  const u32 pk = (u32)rpd[node];                   // issued ||
  const int c16 = csrc16[(long)node*16 + q];       // issued || (safe addr always)
  const float ad = Ad[node];
  const int dg = (int)(pk >> 20);
  const int* rowOv = csrc + (pk & 0xFFFFFu);       // overflow tiles only
  float l = As[node] + ad;
  l = l > 0.f ? l : NEG_SLOPE * l;
  float e = __expf(l);
  float acc[8];
  {
    uint2 hv = ((const uint2*)(Hb + (long)node*32))[q];
    f32x2 p0 = __builtin_amdgcn_cvt_pk_f32_fp8((int)hv.x, 0);
    f32x2 p1 = __builtin_amdgcn_cvt_pk_f32_fp8((int)hv.x, 1);
    f32x2 p2 = __builtin_amdgcn_cvt_pk_f32_fp8((int)hv.y, 0);
    f32x2 p3 = __builtin_amdgcn_cvt_pk_f32_fp8((int)hv.y, 1);
    acc[0]=e*p0.x; acc[1]=e*p0.y; acc[2]=e*p1.x; acc[3]=e*p1.y;
    acc[4]=e*p2.x; acc[5]=e*p2.y; acc[6]=e*p3.x; acc[7]=e*p3.y;
  }
  float den = e;
  for (int jb = 0; jb < dg; jb += 16){
    int m = dg - jb; if (m > 16) m = 16;
    int sj = node;                         // tail lanes: e=0 (no-op), s=node (safe addr)
    if (q < m) sj = (jb == 0) ? c16 : rowOv[jb + q];
    float asv = As[sj];                    // gather issued early, overlaps below
    int s[16];
    #pragma unroll
    for (int i = 0; i < 16; i++) s[i] = __shfl(sj, base + i);
    uint2 h[16];
    #pragma unroll
    for (int i = 0; i < 16; i++) h[i] = ((const uint2*)(Hb + (long)s[i]*32))[q];
    float evq = 0.f;
    if (q < m){
      float l2 = asv + ad;
      l2 = l2 > 0.f ? l2 : NEG_SLOPE * l2;
      evq = __expf(l2);
    }
    float ev[16];
    #pragma unroll
    for (int i = 0; i < 16; i++) ev[i] = __shfl(evq, base + i);
    float dsum = 0.f;
    #pragma unroll
    for (int i = 0; i < 16; i++) dsum += ev[i];
    den += dsum;
    #pragma unroll
    for (int i = 0; i < 16; i++) fma8(acc, ev[i], h[i]);
  }
  float inv = 1.f / den;
  float b[8];
  if (isbf){
    const u16* bp = (const u16*)bv;
    #pragma unroll
    for (int i = 0; i < 8; i++) b[i] = b16f(bp[i*16 + q]);
  } else {
    const float* bp = (const float*)bv;
    #pragma unroll
    for (int i = 0; i < 8; i++) b[i] = bp[i*16 + q];
  }
  float o[8];
  #pragma unroll
  for (int i = 0; i < 8; i++){
    o[i] = fmaf(acc[i], inv, b[i]);
    if (RELU) o[i] = fmaxf(o[i], 0.f);
  }
  uint4 w = make_uint4(pk2(o[0],o[1]), pk2(o[2],o[3]), pk2(o[4],o[5]), pk2(o[6],o[7]));
  *(uint4*)&Ob[(long)node*64 + q*4] = w;
}

// Per-graph mean (counts from bnd), unpermute stored cols, store.
__device__ __forceinline__ void fin_body(const float* __restrict__ ps0,
    const float* __restrict__ ps1, const int* __restrict__ bnd,
    int isbf, void* __restrict__ out, int job)
{
  int t = job*256 + threadIdx.x;
  if (t >= 8192) return;
  int g = t >> 7, pos = t & 127;
  int c = ((pos & 7) << 4) + (pos >> 3);
  int cc = bnd[g+1] - bnd[g];
  float cf = (float)(cc < 1 ? 1 : cc);
  float v0 = ps0[t] / cf, v1 = ps1[t] / cf;
  if (isbf){
    u16* o = (u16*)out;
    o[g*128 + c] = f2b(v0); o[8192 + g*128 + c] = f2b(v1);
  } else {
    float* o = (float*)out;
    o[g*128 + c] = v0; o[8192 + g*128 + c] = v1;
  }
}

// ---------------- cooperative megakernel: whole pipeline, 1 dispatch ----------

struct MegaArgs {
  const u32* x; const int* ei; const int* batch;
  const void *W0, *as0, *ad0, *b0, *W1, *as1, *ad1, *b1;
  u32 *Hb, *Ob; float *As, *Ad;
  u64* breg; int *csrc, *csrc16, *rpd, *bnd, *gcnt;
  float *ps0, *ps1; void* out;
  int N, E, nbuck, gB, aB, nvB, pB;
};

__global__ __launch_bounds__(256) void mega_k(MegaArgs a)
{
  __shared__ __align__(16) char SM[SMBYTES];
  cooperative_groups::grid_group grid = cooperative_groups::this_grid();
  const int nb = (int)gridDim.x;
  const int isbf = detect_body(a.x, SM);

  // P0: gemm0 tiles [0,gB), bnd job gB, part tiles (gB, gB+aB]
  for (int j = blockIdx.x; j < a.gB + 1 + a.aB; j += nb){
    if (j < a.gB)       gemm_body<true,false>(j, isbf, a.x, a.W0, a.as0, a.ad0, a.Hb, a.As, a.Ad, a.N, SM);
    else if (j == a.gB) bnd_body(a.batch, a.bnd, a.N);
    else                part_body(a.ei, a.E, a.nbuck, a.gcnt, a.breg, j - a.gB - 1, SM);
  }
  grid.sync();
  // P1: csr (needs all part buckets)
  for (int j = blockIdx.x; j < a.nbuck; j += nb)
    csr_body(a.gcnt, a.breg, a.rpd, a.csrc, a.csrc16, a.N, j, SM);
  grid.sync();
  // P2: layer-0 gather (+relu)
  for (int j = blockIdx.x; j < a.nvB; j += nb)
    gath_body<true>(a.rpd, a.csrc, a.csrc16, a.As, a.Ad, a.Hb, a.b0, isbf, a.Ob, a.N, j);
  grid.sync();
  // P3: pool0 + gemm1 (independent jobs)
  for (int j = blockIdx.x; j < a.pB + a.gB; j += nb){
    if (j < a.pB) pool_body(a.Ob, a.bnd, a.ps0, a.N, j, SM);
    else          gemm_body<false,true>(j - a.pB, isbf, a.Ob, a.W1, a.as1, a.ad1, a.Hb, a.As, a.Ad, a.N, SM);
  }
  grid.sync();
  // P4: layer-1 gather
  for (int j = blockIdx.x; j < a.nvB; j += nb)
    gath_body<false>(a.rpd, a.csrc, a.csrc16, a.As, a.Ad, a.Hb, a.b1, isbf, a.Ob, a.N, j);
  grid.sync();
  // P5: pool1
  for (int j = blockIdx.x; j < a.pB; j += nb)
    pool_body(a.Ob, a.bnd, a.ps1, a.N, j, SM);
  grid.sync();
  // P6: fin
  for (int j = blockIdx.x; j < 32; j += nb)
    fin_body(a.ps0, a.ps1, a.bnd, isbf, a.out, j);
}

// ---------------- fallback standalone kernels (round-5 proven sequence) ------

__global__ __launch_bounds__(256) void gemmdet0_k(
    const u32* __restrict__ x, const int* __restrict__ batch, int* __restrict__ bnd,
    int* __restrict__ flag,
    const void* __restrict__ W0, const void* __restrict__ as0, const void* __restrict__ ad0,
    u32* __restrict__ Hb, float* __restrict__ As, float* __restrict__ Ad, int N, int gB)
{
  __shared__ __align__(16) char SM[SMBYTES];
  if ((int)blockIdx.x == gB){ bnd_body(batch, bnd, N); return; }
  int isbf = detect_body(x, SM);
  if (blockIdx.x == 0 && threadIdx.x == 0) *flag = isbf;
  gemm_body<true, false>(blockIdx.x, isbf, x, W0, as0, ad0, Hb, As, Ad, N, SM);
}

__global__ __launch_bounds__(256) void part_k(const int* __restrict__ ei, int E, int nbuck,
    int* __restrict__ gcnt, u64* __restrict__ breg)
{
  __shared__ __align__(16) char SM[SMBYTES];
  part_body(ei, E, nbuck, gcnt, breg, blockIdx.x, SM);
}

__global__ __launch_bounds__(256) void csr_k(const int* __restrict__ gcnt,
    const u64* __restrict__ breg,
    int* __restrict__ rpd, int* __restrict__ csrc, int* __restrict__ csrc16, int N)
{
  __shared__ __align__(16) char SM[SMBYTES];
  csr_body(gcnt, breg, rpd, csrc, csrc16, N, blockIdx.x, SM);
}

template<bool RELU>
__global__ __launch_bounds__(256) void gath_k(const int* __restrict__ rpd,
    const int* __restrict__ csrc, const int* __restrict__ csrc16,
    const float* __restrict__ As, const float* __restrict__ Ad,
    const u32* __restrict__ Hb, const void* __restrict__ bv, const int* __restrict__ flag,
    u32* __restrict__ Ob, int N)
{
  gath_body<RELU>(rpd, csrc, csrc16, As, Ad, Hb, bv, *flag, Ob, N, blockIdx.x);
}

__global__ __launch_bounds__(256) void poolgemm1_k(
    const u32* __restrict__ Ob, const int* __restrict__ bnd, float* __restrict__ ps0, int pB,
    const void* __restrict__ W1, const void* __restrict__ as1, const void* __restrict__ ad1,
    const int* __restrict__ flag,
    u32* __restrict__ Hb, float* __restrict__ As, float* __restrict__ Ad, int N)
{
  __shared__ __align__(16) char SM[SMBYTES];
  if ((int)blockIdx.x < pB){ pool_body(Ob, bnd, ps0, N, blockIdx.x, SM); return; }
  gemm_body<false, true>(blockIdx.x - pB, *flag, Ob, W1, as1, ad1, Hb, As, Ad, N, SM);
}

__global__ __launch_bounds__(256) void pool2_k(const u32* __restrict__ Ob,
    const int* __restrict__ bnd, float* __restrict__ psum, int N)
{
  __shared__ __align__(16) char SM[SMBYTES];
  pool_body(Ob, bnd, psum, N, blockIdx.x, SM);
}

__global__ __launch_bounds__(256) void fin_k(const float* __restrict__ ps0,
    const float* __restrict__ ps1, const int* __restrict__ bnd,
    const int* __restrict__ flag, void* __restrict__ out)
{
  fin_body(ps0, ps1, bnd, *flag, out, blockIdx.x);
}

extern "C" void kernel_launch(void* const* d_in, const int* in_sizes, int n_in,
                              void* d_out, int out_size, void* d_ws, size_t ws_size,
                              hipStream_t stream)
{
  const void* x    = d_in[0];
  const int* ei    = (const int*)d_in[1];
  const int* batch = (const int*)d_in[3];
  const void* W0  = d_in[4];
  const void* as0 = d_in[5];
  const void* ad0 = d_in[6];
  const void* b0  = d_in[7];
  const void* W1  = d_in[8];
  const void* as1 = d_in[9];
  const void* ad1 = d_in[10];
  const void* b1  = d_in[11];

  const int N  = in_sizes[0] / 128;   // 50000
  const int E  = in_sizes[1] / 2;     // 600000
  const int nbuck = (N + 255) >> 8;   // 196 (must be <= 256)

  char* ws = (char*)d_ws;
  size_t off = 0;
  auto al = [&](size_t bytes){ size_t o = off; off += (bytes + 255) & ~(size_t)255; return o; };
  u32*   Hb    = (u32*)(ws + al((size_t)N*32*4));          // 6.4 MB fp8 H (perm cols)
  u32*   Ob    = (u32*)(ws + al((size_t)N*64*4));          // 12.8 MB bf16 out (perm cols)
  float* As    = (float*)(ws + al((size_t)N*4));
  float* Ad    = (float*)(ws + al((size_t)N*4));
  u64*   breg  = (u64*)(ws + al((size_t)nbuck*BSTRIDE*8)); // 6.4 MB bucketed (dst,src)
  int*   csrc  = (int*)(ws + al((size_t)nbuck*BSTRIDE*4)); // 3.2 MB overflow CSR srcs
  int*   csrc16= (int*)(ws + al((size_t)N*16*4));          // 3.2 MB first-tile srcs
  int*   rpd   = (int*)(ws + al((size_t)N*4));             // rowptr | deg<<20
  int*   bnd   = (int*)(ws + al(512));                     // graph starts [65] (full 512B!)
  // contiguous zero region: ps0 + ps1 + gcnt (one memset)
  const size_t zbytes = 2*64*128*4 + 256*4;
  char*  z0    = ws + al(zbytes);
  float* ps0   = (float*)z0;
  float* ps1   = ps0 + 8192;
  int*   gcnt  = (int*)(ps1 + 8192);
  int*   flag  = (int*)(ws + al(256));
  if (off > ws_size) return;

  hipMemsetAsync(z0, 0, zbytes, stream);

  const int gB   = (N/16 + 3) / 4;        // gemm tiles (782)
  const int aB   = (E + 2047) / 2048;     // part tiles (293)
  const int nvB16= (N*16 + 255) / 256;    // gath tiles (3125)
  const int pB   = (N + 127) / 128;       // pool tiles (391)

  MegaArgs A;
  A.x = (const u32*)x; A.ei = ei; A.batch = batch;
  A.W0 = W0; A.as0 = as0; A.ad0 = ad0; A.b0 = b0;
  A.W1 = W1; A.as1 = as1; A.ad1 = ad1; A.b1 = b1;
  A.Hb = Hb; A.Ob = Ob; A.As = As; A.Ad = Ad;
  A.breg = breg; A.csrc = csrc; A.csrc16 = csrc16; A.rpd = rpd; A.bnd = bnd; A.gcnt = gcnt;
  A.ps0 = ps0; A.ps1 = ps1; A.out = d_out;
  A.N = N; A.E = E; A.nbuck = nbuck; A.gB = gB; A.aB = aB; A.nvB = nvB16; A.pB = pB;

  int occ = 0;
  hipError_t qerr = hipOccupancyMaxActiveBlocksPerMultiprocessor(
      &occ, (const void*)mega_k, 256, 0);
  if (qerr == hipSuccess && occ >= 1){
    int grid = occ * 256;              // co-resident capacity (256 CUs)
    if (grid > 512) grid = 512;        // R8/R9: grid 1024 regime measured 2.5x
                                       // slower than R7's 512 — never exceed it.
    void* kargs[] = { (void*)&A };
    hipError_t err = hipLaunchCooperativeKernel((const void*)mega_k,
        dim3(grid), dim3(256), kargs, 0, stream);
    if (err == hipSuccess) return;
  }

  // ---- fallback: proven round-5 dispatch sequence (same bodies) ----
  gemmdet0_k<<<gB + 1, 256, 0, stream>>>((const u32*)x, batch, bnd, flag,
      W0, as0, ad0, Hb, As, Ad, N, gB);
  part_k<<<aB, 256, 0, stream>>>(ei, E, nbuck, gcnt, breg);
  csr_k<<<nbuck, 256, 0, stream>>>(gcnt, breg, rpd, csrc, csrc16, N);
  gath_k<true><<<nvB16, 256, 0, stream>>>(rpd, csrc, csrc16, As, Ad, Hb, b0, flag, Ob, N);
  poolgemm1_k<<<pB + gB, 256, 0, stream>>>(Ob, bnd, ps0, pB,
      W1, as1, ad1, flag, Hb, As, Ad, N);
  gath_k<false><<<nvB16, 256, 0, stream>>>(rpd, csrc, csrc16, As, Ad, Hb, b1, flag, Ob, N);
  pool2_k<<<pB, 256, 0, stream>>>(Ob, bnd, ps1, N);
  fin_k<<<32, 256, 0, stream>>>(ps0, ps1, bnd, flag, d_out);
}